// Round 6
// baseline (733.249 us; speedup 1.0000x reference)
//
#include <hip/hip_runtime.h>
#include <math.h>

#define NN 50000
#define NE 500000
#define EEDG 550000          // NE + NN self loops
#define SDIM 128             // STRUCT
#define MDIM 768             // SEM
#define HIDD 128             // HID
#define NHEADS 4
#define INDIM 896            // STRUCT + SEM
#define H1D 512              // HEADS*HID
#define SCAN_NB 196          // ceil(NN/256)
#define MP 50048             // NN padded to 128*391
#define MT 391               // row tiles of 128

typedef unsigned short u16;
typedef unsigned int u32;
typedef __attribute__((ext_vector_type(8))) short short8;
typedef __attribute__((ext_vector_type(4))) float f32x4;

// ---------------- bf16 helpers ----------------
__device__ __forceinline__ u16 f2bf(float f) {
    union { float f; u32 u; } v; v.f = f;
    u32 r = v.u + 0x7FFFu + ((v.u >> 16) & 1u);
    return (u16)(r >> 16);
}
__device__ __forceinline__ float bf2f(u16 h) {
    union { u32 u; float f; } v; v.u = ((u32)h) << 16;
    return v.f;
}

__device__ __forceinline__ void gl_lds16(const u16* g, u16* l) {
    __builtin_amdgcn_global_load_lds(
        (const __attribute__((address_space(1))) void*)g,
        (__attribute__((address_space(3))) void*)l, 16, 0, 0);
}

// ---------------- utility ----------------
__device__ __forceinline__ void edge_sd(const int* __restrict__ ei, int e, int& s, int& d) {
    if (e < NE) { s = ei[e]; d = ei[NE + e]; }
    else        { s = e - NE; d = e - NE; }
}

__global__ void fillk(float* __restrict__ p, float v, long count) {
    long i = (long)blockIdx.x * blockDim.x + threadIdx.x;
    long stride = (long)gridDim.x * blockDim.x;
    for (; i < count; i += stride) p[i] = v;
}

__global__ void fillk_i(int* __restrict__ p, int v, long count) {
    long i = (long)blockIdx.x * blockDim.x + threadIdx.x;
    long stride = (long)gridDim.x * blockDim.x;
    for (; i < count; i += stride) p[i] = v;
}

// ---------------- casts ----------------
__global__ __launch_bounds__(256) void cast_pad_x(const float4* __restrict__ x4, u16* __restrict__ xb) {
    const long total = (long)MP * 224;
    long i = (long)blockIdx.x * blockDim.x + threadIdx.x;
    long stride = (long)gridDim.x * blockDim.x;
    for (; i < total; i += stride) {
        int row = (int)(i / 224);
        int c4 = (int)(i - (long)row * 224);
        float4 v = make_float4(0.f, 0.f, 0.f, 0.f);
        if (row < NN) v = x4[(size_t)row * 224 + c4];
        short4 o;
        o.x = (short)f2bf(v.x); o.y = (short)f2bf(v.y);
        o.z = (short)f2bf(v.z); o.w = (short)f2bf(v.w);
        *(short4*)(xb + (size_t)row * 896 + c4 * 4) = o;
    }
}

// W (K x N f32, row-major) -> Wb (N x K bf16) transposed cast
__global__ __launch_bounds__(256) void cast_wT(const float* __restrict__ W, u16* __restrict__ Wb, int K, int N) {
    int k = blockIdx.x * 4 + (threadIdx.x >> 6);
    int n = blockIdx.y * 64 + (threadIdx.x & 63);
    if (k < K && n < N) Wb[(size_t)n * K + k] = f2bf(W[(size_t)k * N + n]);
}

// ---------------- CSR build ----------------
__global__ __launch_bounds__(256) void count_deg(const int* __restrict__ ei, int* __restrict__ deg) {
    int e = blockIdx.x * 256 + threadIdx.x;
    if (e >= EEDG) return;
    int d = e < NE ? ei[NE + e] : e - NE;
    atomicAdd(&deg[d], 1);
}

__global__ __launch_bounds__(256) void scan_bsum(const int* __restrict__ deg, int* __restrict__ part) {
    __shared__ int s[256];
    int t = threadIdx.x;
    int idx = blockIdx.x * 256 + t;
    s[t] = idx < NN ? deg[idx] : 0;
    __syncthreads();
    for (int off = 128; off; off >>= 1) {
        if (t < off) s[t] += s[t + off];
        __syncthreads();
    }
    if (t == 0) part[blockIdx.x] = s[0];
}

__global__ __launch_bounds__(256) void scan_part(int* __restrict__ part) {
    __shared__ int s[256];
    int t = threadIdx.x;
    int v = t < SCAN_NB ? part[t] : 0;
    s[t] = v;
    __syncthreads();
    for (int off = 1; off < 256; off <<= 1) {
        int x = t >= off ? s[t - off] : 0;
        __syncthreads();
        s[t] += x;
        __syncthreads();
    }
    if (t < SCAN_NB) part[t] = s[t] - v;   // exclusive
}

__global__ __launch_bounds__(256) void scan_write(const int* __restrict__ deg, const int* __restrict__ part,
                                                  int* __restrict__ rowptr) {
    __shared__ int s[256];
    int t = threadIdx.x;
    int idx = blockIdx.x * 256 + t;
    int v = idx < NN ? deg[idx] : 0;
    s[t] = v;
    __syncthreads();
    for (int off = 1; off < 256; off <<= 1) {
        int x = t >= off ? s[t - off] : 0;
        __syncthreads();
        s[t] += x;
        __syncthreads();
    }
    if (idx < NN) rowptr[idx] = part[blockIdx.x] + s[t] - v;
    if (idx == NN - 1) rowptr[NN] = EEDG;
}

__global__ __launch_bounds__(256) void fill_csr(const int* __restrict__ ei, const int* __restrict__ rowptr,
                                                int* __restrict__ cur, int* __restrict__ esrc) {
    int e = blockIdx.x * 256 + threadIdx.x;
    if (e >= EEDG) return;
    int s, d;
    edge_sd(ei, e, s, d);
    int p = rowptr[d] + atomicAdd(&cur[d], 1);
    esrc[p] = s;
}

// ---------------- MFMA bf16 GEMM body (single col tile) ----------------
template<int OUT_BF16>
__device__ __forceinline__ void gemm_body(
    u16* __restrict__ Asm, u16* __restrict__ Bsm,
    const u16* __restrict__ A1, int lda1, int K1,
    const u16* __restrict__ A2, int lda2, int K2,
    const u16* __restrict__ Bw,
    void* __restrict__ Cout, int ldc,
    const float* __restrict__ bias, int row0, int col0)
{
    const int tid = threadIdx.x;
    const int wave = tid >> 6, lane = tid & 63;
    const int wr = wave >> 1, wc = wave & 1;
    const int K = K1 + K2;
    const int srow = tid >> 2;
    const int skp = (tid & 3) * 8;
    const int l15 = lane & 15, l4 = lane >> 4;

    f32x4 acc[4][4];
    #pragma unroll
    for (int i = 0; i < 4; ++i)
        #pragma unroll
        for (int j = 0; j < 4; ++j)
            acc[i][j] = (f32x4){0.f, 0.f, 0.f, 0.f};

    for (int k0 = 0; k0 < K; k0 += 32) {
        const u16* Ab; int la; int kk;
        if (k0 < K1) { Ab = A1; la = lda1; kk = k0; }
        else         { Ab = A2; la = lda2; kk = k0 - K1; }
        gl_lds16(Ab + (size_t)(row0 + srow) * la + kk + skp,      Asm + srow * 32 + skp);
        gl_lds16(Ab + (size_t)(row0 + srow + 64) * la + kk + skp, Asm + (srow + 64) * 32 + skp);
        gl_lds16(Bw + (size_t)(col0 + srow) * K + k0 + skp,       Bsm + srow * 32 + skp);
        gl_lds16(Bw + (size_t)(col0 + srow + 64) * K + k0 + skp,  Bsm + (srow + 64) * 32 + skp);
        __syncthreads();
        short8 af[4], bfr[4];
        #pragma unroll
        for (int m = 0; m < 4; ++m)
            af[m] = *(const short8*)(Asm + (wr * 64 + m * 16 + l15) * 32 + l4 * 8);
        #pragma unroll
        for (int n = 0; n < 4; ++n)
            bfr[n] = *(const short8*)(Bsm + (wc * 64 + n * 16 + l15) * 32 + l4 * 8);
        #pragma unroll
        for (int m = 0; m < 4; ++m)
            #pragma unroll
            for (int n = 0; n < 4; ++n)
                acc[m][n] = __builtin_amdgcn_mfma_f32_16x16x32_bf16(af[m], bfr[n], acc[m][n], 0, 0, 0);
        __syncthreads();
    }
    #pragma unroll
    for (int m = 0; m < 4; ++m) {
        int r = row0 + wr * 64 + m * 16 + l4 * 4;
        #pragma unroll
        for (int n = 0; n < 4; ++n) {
            int c = col0 + wc * 64 + n * 16 + l15;
            float bv = bias ? bias[c] : 0.f;
            #pragma unroll
            for (int q = 0; q < 4; ++q) {
                float v = acc[m][n][q] + bv;
                if (OUT_BF16) ((u16*)Cout)[(size_t)(r + q) * ldc + c] = f2bf(v);
                else          ((float*)Cout)[(size_t)(r + q) * ldc + c] = v;
            }
        }
    }
}

template<int OUT_BF16>
__global__ __launch_bounds__(256) void gemm_mfma(
    const u16* __restrict__ A1, int lda1, int K1,
    const u16* __restrict__ A2, int lda2, int K2,
    const u16* __restrict__ Bw,
    void* __restrict__ Cout, int ldc,
    const float* __restrict__ bias)
{
    __shared__ u16 Asm[128 * 32];
    __shared__ u16 Bsm[128 * 32];
    gemm_body<OUT_BF16>(Asm, Bsm, A1, lda1, K1, A2, lda2, K2, Bw, Cout, ldc, bias,
                        blockIdx.y * 128, blockIdx.x * 128);
}

// ---------------- dual-column-tile GEMM: one A panel, two B tiles ----------------
// Computes C0[row0:+128, +128cols] and C1[row0:+128, +128cols] sharing the A stage.
// B0/B1: 128 x K each (rows of W^T). blockIdx.x advances both B (rows) and C (cols) by 256.
__global__ __launch_bounds__(256) void gemm_dual(
    const u16* __restrict__ A1, int lda1, int K1,
    const u16* __restrict__ A2, int lda2, int K2,
    const u16* __restrict__ B0, const u16* __restrict__ B1,
    u16* __restrict__ C0, u16* __restrict__ C1, int ldc)
{
    __shared__ u16 Asm[128 * 32];
    __shared__ u16 B0sm[128 * 32];
    __shared__ u16 B1sm[128 * 32];
    const int tid = threadIdx.x;
    const int wave = tid >> 6, lane = tid & 63;
    const int wr = wave >> 1, wc = wave & 1;
    const int row0 = blockIdx.y * 128;
    const int K = K1 + K2;
    const int l15 = lane & 15, l4 = lane >> 4;
    // blockIdx.x super-column advance
    size_t badv = (size_t)blockIdx.x * 256 * K;
    size_t cadv = (size_t)blockIdx.x * 256;
    B0 += badv; B1 += badv;
    C0 += cadv; C1 += cadv;
    // staging: 512 16B-chunks per matrix, 2 per thread
    const int r0s = tid >> 1;               // chunk pair row for A/B: rows tid>>1 ... hmm use generic
    const int ca = tid, cb = tid + 256;
    const int ra = ca >> 2, ka = (ca & 3) * 8;
    const int rb = cb >> 2, kb_ = (cb & 3) * 8;
    (void)r0s;

    f32x4 acc0[4][4], acc1[4][4];
    #pragma unroll
    for (int i = 0; i < 4; ++i)
        #pragma unroll
        for (int j = 0; j < 4; ++j) {
            acc0[i][j] = (f32x4){0.f, 0.f, 0.f, 0.f};
            acc1[i][j] = (f32x4){0.f, 0.f, 0.f, 0.f};
        }

    for (int k0 = 0; k0 < K; k0 += 32) {
        const u16* Ab; int la; int kk;
        if (k0 < K1) { Ab = A1; la = lda1; kk = k0; }
        else         { Ab = A2; la = lda2; kk = k0 - K1; }
        gl_lds16(Ab + (size_t)(row0 + ra) * la + kk + ka,  Asm + ra * 32 + ka);
        gl_lds16(Ab + (size_t)(row0 + rb) * la + kk + kb_, Asm + rb * 32 + kb_);
        gl_lds16(B0 + (size_t)ra * K + k0 + ka,  B0sm + ra * 32 + ka);
        gl_lds16(B0 + (size_t)rb * K + k0 + kb_, B0sm + rb * 32 + kb_);
        gl_lds16(B1 + (size_t)ra * K + k0 + ka,  B1sm + ra * 32 + ka);
        gl_lds16(B1 + (size_t)rb * K + k0 + kb_, B1sm + rb * 32 + kb_);
        __syncthreads();
        short8 af[4], b0f[4], b1f[4];
        #pragma unroll
        for (int m = 0; m < 4; ++m)
            af[m] = *(const short8*)(Asm + (wr * 64 + m * 16 + l15) * 32 + l4 * 8);
        #pragma unroll
        for (int n = 0; n < 4; ++n) {
            b0f[n] = *(const short8*)(B0sm + (wc * 64 + n * 16 + l15) * 32 + l4 * 8);
            b1f[n] = *(const short8*)(B1sm + (wc * 64 + n * 16 + l15) * 32 + l4 * 8);
        }
        #pragma unroll
        for (int m = 0; m < 4; ++m)
            #pragma unroll
            for (int n = 0; n < 4; ++n) {
                acc0[m][n] = __builtin_amdgcn_mfma_f32_16x16x32_bf16(af[m], b0f[n], acc0[m][n], 0, 0, 0);
                acc1[m][n] = __builtin_amdgcn_mfma_f32_16x16x32_bf16(af[m], b1f[n], acc1[m][n], 0, 0, 0);
            }
        __syncthreads();
    }
    #pragma unroll
    for (int m = 0; m < 4; ++m) {
        int r = row0 + wr * 64 + m * 16 + l4 * 4;
        #pragma unroll
        for (int n = 0; n < 4; ++n) {
            int c = wc * 64 + n * 16 + l15;
            #pragma unroll
            for (int q = 0; q < 4; ++q) {
                C0[(size_t)(r + q) * ldc + c] = f2bf(acc0[m][n][q]);
                C1[(size_t)(r + q) * ldc + c] = f2bf(acc1[m][n][q]);
            }
        }
    }
}

// ---------------- node cross-attention (bf16): V *= sigmoid(dot(Q,K)) ----------------
__global__ __launch_bounds__(128) void node_attn_b(const u16* __restrict__ Q,
                                                   const u16* __restrict__ K,
                                                   u16* __restrict__ V)
{
    int nd = blockIdx.x;
    int t = threadIdx.x;
    size_t base = (size_t)nd * HIDD;
    float p = bf2f(Q[base + t]) * bf2f(K[base + t]);
    #pragma unroll
    for (int off = 32; off; off >>= 1) p += __shfl_down(p, off);
    __shared__ float sm[2];
    if ((t & 63) == 0) sm[t >> 6] = p;
    __syncthreads();
    float s = sm[0] + sm[1];
    float sig = 1.f / (1.f + expf(-s));
    V[base + t] = f2bf(bf2f(V[base + t]) * sig);
}

// ---------------- GAT attention-coefficient dots ----------------
__global__ __launch_bounds__(256) void att_dots1_b(const u16* __restrict__ h1,
    const float* __restrict__ asv, const float* __restrict__ adv,
    float* __restrict__ a_src, float* __restrict__ a_dst)
{
    int nd = blockIdx.x;
    int t = threadIdx.x;
    int w = t >> 6, l = t & 63;
    const u16* hr = h1 + (size_t)nd * H1D + w * HIDD;
    const float* sv = asv + w * HIDD;
    const float* dv = adv + w * HIDD;
    float h0v = bf2f(hr[l]), h1v = bf2f(hr[l + 64]);
    float ps = h0v * sv[l] + h1v * sv[l + 64];
    float pd = h0v * dv[l] + h1v * dv[l + 64];
    #pragma unroll
    for (int off = 32; off; off >>= 1) {
        ps += __shfl_down(ps, off);
        pd += __shfl_down(pd, off);
    }
    if (l == 0) { a_src[nd * NHEADS + w] = ps; a_dst[nd * NHEADS + w] = pd; }
}

__global__ __launch_bounds__(128) void att_dots2_b(const u16* __restrict__ h2,
    const float* __restrict__ sv, const float* __restrict__ dv,
    float* __restrict__ a_src, float* __restrict__ a_dst)
{
    int nd = blockIdx.x;
    int t = threadIdx.x;
    float hv = bf2f(h2[(size_t)nd * HIDD + t]);
    float ps = hv * sv[t], pd = hv * dv[t];
    #pragma unroll
    for (int off = 32; off; off >>= 1) {
        ps += __shfl_down(ps, off);
        pd += __shfl_down(pd, off);
    }
    __shared__ float sm[4];
    if ((t & 63) == 0) { sm[t >> 6] = ps; sm[2 + (t >> 6)] = pd; }
    __syncthreads();
    if (t == 0) { a_src[nd] = sm[0] + sm[1]; a_dst[nd] = sm[2] + sm[3]; }
}

// ---------------- fused softmax + gather aggregation ----------------
// layer 1: block per dst, chunks of 64 edges; per-edge softmax computed ONCE,
// consumed via LDS broadcast; gather loop 4-unrolled for MLP.
__global__ __launch_bounds__(256) void agg1_f(const int* __restrict__ rowptr, const int* __restrict__ esrc,
    const float* __restrict__ asrc, const float* __restrict__ adst,
    const u16* __restrict__ h1b, const float* __restrict__ bias, u16* __restrict__ o1b)
{
    __shared__ int   s_src[64];
    __shared__ float s_att[64 * NHEADS];
    int d = blockIdx.x;
    int t = threadIdx.x;
    int c0 = t * 2;
    int h = t >> 6;               // head for this thread's output columns
    int eh = t & 3;               // head this thread computes exp for
    int ee = t >> 2;              // edge slot this thread computes exp for
    int beg = rowptr[d], end = rowptr[d + 1];
    float ad_eh = adst[d * NHEADS + eh];
    float n0 = 0.f, n1 = 0.f, den = 0.f;
    for (int i0 = beg; i0 < end; i0 += 64) {
        int m = min(64, end - i0);
        float ex = 0.f; int s = 0;
        if (ee < m) {
            s = esrc[i0 + ee];
            float a = asrc[s * NHEADS + eh] + ad_eh;
            a = a >= 0.f ? a : 0.2f * a;
            ex = expf(a);
        }
        s_att[ee * NHEADS + eh] = ex;
        if (eh == 0) s_src[ee] = s;
        __syncthreads();
        int j = 0;
        for (; j + 3 < m; j += 4) {
            int sA = s_src[j], sB = s_src[j + 1], sC = s_src[j + 2], sD = s_src[j + 3];
            float aA = s_att[j * NHEADS + h],       aB = s_att[(j + 1) * NHEADS + h];
            float aC = s_att[(j + 2) * NHEADS + h], aD = s_att[(j + 3) * NHEADS + h];
            u32 pA = *(const u32*)(h1b + (size_t)sA * H1D + c0);
            u32 pB = *(const u32*)(h1b + (size_t)sB * H1D + c0);
            u32 pC = *(const u32*)(h1b + (size_t)sC * H1D + c0);
            u32 pD = *(const u32*)(h1b + (size_t)sD * H1D + c0);
            den += (aA + aB) + (aC + aD);
            n0 = fmaf(bf2f((u16)pA), aA, n0);
            n1 = fmaf(bf2f((u16)(pA >> 16)), aA, n1);
            n0 = fmaf(bf2f((u16)pB), aB, n0);
            n1 = fmaf(bf2f((u16)(pB >> 16)), aB, n1);
            n0 = fmaf(bf2f((u16)pC), aC, n0);
            n1 = fmaf(bf2f((u16)(pC >> 16)), aC, n1);
            n0 = fmaf(bf2f((u16)pD), aD, n0);
            n1 = fmaf(bf2f((u16)(pD >> 16)), aD, n1);
        }
        for (; j < m; ++j) {
            int sA = s_src[j];
            float aA = s_att[j * NHEADS + h];
            u32 pA = *(const u32*)(h1b + (size_t)sA * H1D + c0);
            den += aA;
            n0 = fmaf(bf2f((u16)pA), aA, n0);
            n1 = fmaf(bf2f((u16)(pA >> 16)), aA, n1);
        }
        __syncthreads();
    }
    float invd = 1.f / (den + 1e-16f);
    float a0o = n0 * invd + bias[c0];
    float a1o = n1 * invd + bias[c0 + 1];
    u32 o = (u32)f2bf(a0o) | ((u32)f2bf(a1o) << 16);
    *(u32*)(o1b + (size_t)d * H1D + c0) = o;
}

// layer 2: wave per dst (4/block), shfl broadcast, 4-unrolled gather.
__global__ __launch_bounds__(256) void agg2_f(const int* __restrict__ rowptr, const int* __restrict__ esrc,
    const float* __restrict__ asrc, const float* __restrict__ adst,
    const u16* __restrict__ h2b, const float* __restrict__ bias, float* __restrict__ o2)
{
    int w = threadIdx.x >> 6, l = threadIdx.x & 63;
    int d = blockIdx.x * 4 + w;
    if (d >= NN) return;
    int c0 = l * 2;
    int beg = rowptr[d], end = rowptr[d + 1];
    float ad = adst[d];
    float n0 = 0.f, n1 = 0.f, den = 0.f;
    for (int i0 = beg; i0 < end; i0 += 64) {
        int m = min(64, end - i0);
        float ex = 0.f; int s = 0;
        if (l < m) {
            s = esrc[i0 + l];
            float a = asrc[s] + ad;
            a = a >= 0.f ? a : 0.2f * a;
            ex = expf(a);
        }
        int j = 0;
        for (; j + 3 < m; j += 4) {
            int sA = __shfl(s, j), sB = __shfl(s, j + 1), sC = __shfl(s, j + 2), sD = __shfl(s, j + 3);
            float aA = __shfl(ex, j), aB = __shfl(ex, j + 1), aC = __shfl(ex, j + 2), aD = __shfl(ex, j + 3);
            u32 pA = *(const u32*)(h2b + (size_t)sA * HIDD + c0);
            u32 pB = *(const u32*)(h2b + (size_t)sB * HIDD + c0);
            u32 pC = *(const u32*)(h2b + (size_t)sC * HIDD + c0);
            u32 pD = *(const u32*)(h2b + (size_t)sD * HIDD + c0);
            den += (aA + aB) + (aC + aD);
            n0 = fmaf(bf2f((u16)pA), aA, n0);
            n1 = fmaf(bf2f((u16)(pA >> 16)), aA, n1);
            n0 = fmaf(bf2f((u16)pB), aB, n0);
            n1 = fmaf(bf2f((u16)(pB >> 16)), aB, n1);
            n0 = fmaf(bf2f((u16)pC), aC, n0);
            n1 = fmaf(bf2f((u16)(pC >> 16)), aC, n1);
            n0 = fmaf(bf2f((u16)pD), aD, n0);
            n1 = fmaf(bf2f((u16)(pD >> 16)), aD, n1);
        }
        for (; j < m; ++j) {
            int sA = __shfl(s, j);
            float aA = __shfl(ex, j);
            u32 pA = *(const u32*)(h2b + (size_t)sA * HIDD + c0);
            den += aA;
            n0 = fmaf(bf2f((u16)pA), aA, n0);
            n1 = fmaf(bf2f((u16)(pA >> 16)), aA, n1);
        }
    }
    float invd = 1.f / (den + 1e-16f);
    o2[(size_t)d * HIDD + c0]     = n0 * invd + bias[c0];
    o2[(size_t)d * HIDD + c0 + 1] = n1 * invd + bias[c0 + 1];
}

// ---------------- graph norm ----------------
__global__ void colstat_b(const u16* __restrict__ x, float* __restrict__ msum,
                          float* __restrict__ vsum, int n, int rpb)
{
    int C = blockDim.x;
    int c = threadIdx.x;
    int r0 = blockIdx.x * rpb;
    int r1 = min(n, r0 + rpb);
    float s = 0.f, s2 = 0.f;
    for (int r = r0; r < r1; ++r) {
        float v = bf2f(x[(size_t)r * C + c]);
        s += v;
        s2 += v * v;
    }
    atomicAdd(&msum[c], s);
    atomicAdd(&vsum[c], s2);
}

__global__ void apply_norm_elu_b(u16* __restrict__ x, const float* __restrict__ msum,
                                 const float* __restrict__ vsum, const float* __restrict__ ms,
                                 const float* __restrict__ w, const float* __restrict__ b,
                                 int n, int rpb)
{
    int C = blockDim.x;
    int c = threadIdx.x;
    const float invn = 1.f / (float)NN;
    float mean = msum[c] * invn;
    float sub = mean * ms[c];
    float var = vsum[c] * invn - 2.f * sub * mean + sub * sub;
    float inv = rsqrtf(var + 1e-5f);
    float wc = w[c] * inv, bc = b[c];
    int r0 = blockIdx.x * rpb;
    int r1 = min(n, r0 + rpb);
    for (int r = r0; r < r1; ++r) {
        float v = (bf2f(x[(size_t)r * C + c]) - sub) * wc + bc;
        v = v > 0.f ? v : expm1f(v);
        x[(size_t)r * C + c] = f2bf(v);
    }
}

__global__ void colstat(const float* __restrict__ x, float* __restrict__ msum,
                        float* __restrict__ vsum, int n, int rpb)
{
    int C = blockDim.x;
    int c = threadIdx.x;
    int r0 = blockIdx.x * rpb;
    int r1 = min(n, r0 + rpb);
    float s = 0.f, s2 = 0.f;
    for (int r = r0; r < r1; ++r) {
        float v = x[(size_t)r * C + c];
        s += v;
        s2 += v * v;
    }
    atomicAdd(&msum[c], s);
    atomicAdd(&vsum[c], s2);
}

// ---------------- fused norm2 + ELU + final projection ----------------
__global__ __launch_bounds__(128) void norm2_proj(const float* __restrict__ o2,
    const float* __restrict__ msum, const float* __restrict__ vsum,
    const float* __restrict__ ms, const float* __restrict__ w, const float* __restrict__ b,
    const float* __restrict__ Wn, const float* __restrict__ bn, float* __restrict__ out)
{
    int nd = blockIdx.x;
    int t = threadIdx.x;
    const float invn = 1.f / (float)NN;
    float mean = msum[t] * invn;
    float sub = mean * ms[t];
    float var = vsum[t] * invn - 2.f * sub * mean + sub * sub;
    float inv = rsqrtf(var + 1e-5f);
    float v = (o2[(size_t)nd * HIDD + t] - sub) * w[t] * inv + b[t];
    v = v > 0.f ? v : expm1f(v);
    float p0 = v * Wn[t * 2], p1 = v * Wn[t * 2 + 1];
    #pragma unroll
    for (int off = 32; off; off >>= 1) {
        p0 += __shfl_down(p0, off);
        p1 += __shfl_down(p1, off);
    }
    __shared__ float sm[4];
    if ((t & 63) == 0) { sm[t >> 6] = p0; sm[2 + (t >> 6)] = p1; }
    __syncthreads();
    if (t == 0) {
        out[nd * 2 + 0] = sm[0] + sm[1] + bn[0];
        out[nd * 2 + 1] = sm[2] + sm[3] + bn[1];
    }
}

// ---------------- host launch ----------------
extern "C" void kernel_launch(void* const* d_in, const int* in_sizes, int n_in,
                              void* d_out, int out_size, void* d_ws, size_t ws_size,
                              hipStream_t stream)
{
    const float* x   = (const float*)d_in[0];
    const int*   ei  = (const int*)d_in[1];
    const float* Wq  = (const float*)d_in[2];
    const float* Wk  = (const float*)d_in[3];
    const float* Wv  = (const float*)d_in[4];
    const float* Wo  = (const float*)d_in[5];
    const float* bo  = (const float*)d_in[6];
    const float* W1  = (const float*)d_in[7];
    const float* as1 = (const float*)d_in[8];
    const float* ad1 = (const float*)d_in[9];
    const float* b1  = (const float*)d_in[10];
    const float* g1w = (const float*)d_in[11];
    const float* g1b = (const float*)d_in[12];
    const float* g1m = (const float*)d_in[13];
    const float* W2  = (const float*)d_in[14];
    const float* as2 = (const float*)d_in[15];
    const float* ad2 = (const float*)d_in[16];
    const float* b2  = (const float*)d_in[17];
    const float* g2w = (const float*)d_in[18];
    const float* g2b = (const float*)d_in[19];
    const float* g2m = (const float*)d_in[20];
    const float* Wn  = (const float*)d_in[21];
    const float* bn  = (const float*)d_in[22];
    float* out = (float*)d_out;

    // ---- workspace layout ----
    u16* usw = (u16*)d_ws;
    size_t uo = 0;
    u16* xb  = usw + uo; uo += (size_t)MP * 896;
    u16* h1b = usw + uo; uo += (size_t)MP * 512;
    u16* qb  = usw + uo; uo += (size_t)MP * 128;
    u16* kb  = usw + uo; uo += (size_t)MP * 128;   // later h2b
    u16* vb  = usw + uo; uo += (size_t)MP * 128;
    u16* o1b = usw + uo; uo += (size_t)MP * 512;
    u16* wqT = usw + uo; uo += 128 * 128;
    u16* wkT = usw + uo; uo += 128 * 768;
    u16* wvT = usw + uo; uo += 128 * 768;
    u16* woT = usw + uo; uo += 128 * 256;
    u16* w1T = usw + uo; uo += 512 * 896;
    u16* w2T = usw + uo; uo += 128 * 512;
    float* fws = (float*)(usw + uo);
    size_t fo = 0;
    float* asrc = fws + fo; fo += NN * NHEADS;
    float* adst = fws + fo; fo += NN * NHEADS;
    float* msum = fws + fo; fo += 512;
    float* vsum = fws + fo; fo += 512;
    int* iws = (int*)(fws + fo);
    size_t io = 0;
    int* rowptr = iws + io; io += NN + 1;
    int* degcur = iws + io; io += 2 * NN;     // [deg | cur] zeroed together
    int* esrc   = iws + io; io += EEDG;
    int* spart  = iws + io; io += 256;
    int* cur    = degcur + NN;
    // aliases: xb region free after h1 GEMM
    float* o2  = (float*)xb;
    u16* h0b = qb;   // reuse q after node_attn
    u16* h2b = kb;   // reuse k after node_attn

    const int EB = (EEDG + 255) / 256;

    // --- weight casts (transposed to N x K) ---
    cast_wT<<<dim3(32, 2),   256, 0, stream>>>(Wq, wqT, 128, 128);
    cast_wT<<<dim3(192, 2),  256, 0, stream>>>(Wk, wkT, 768, 128);
    cast_wT<<<dim3(192, 2),  256, 0, stream>>>(Wv, wvT, 768, 128);
    cast_wT<<<dim3(64, 2),   256, 0, stream>>>(Wo, woT, 256, 128);
    cast_wT<<<dim3(224, 8),  256, 0, stream>>>(W1, w1T, 896, 512);
    cast_wT<<<dim3(128, 2),  256, 0, stream>>>(W2, w2T, 512, 128);
    cast_pad_x<<<8192, 256, 0, stream>>>((const float4*)x, xb);

    // --- CSR build (esrc only) ---
    fillk_i<<<392, 256, 0, stream>>>(degcur, 0, 2 * NN);
    count_deg<<<EB, 256, 0, stream>>>(ei, degcur);
    scan_bsum<<<SCAN_NB, 256, 0, stream>>>(degcur, spart);
    scan_part<<<1, 256, 0, stream>>>(spart);
    scan_write<<<SCAN_NB, 256, 0, stream>>>(degcur, spart, rowptr);
    fill_csr<<<EB, 256, 0, stream>>>(ei, rowptr, cur, esrc);

    // --- cross attention: Q single, K|V dual (shared x_sem panel), gate ---
    gemm_mfma<1><<<dim3(1, MT), 256, 0, stream>>>(xb, 896, 128, (const u16*)nullptr, 0, 0, wqT, qb, 128, nullptr);
    gemm_dual<<<dim3(1, MT), 256, 0, stream>>>(xb + 128, 896, 768, (const u16*)nullptr, 0, 0,
                                               wkT, wvT, kb, vb, 128);
    node_attn_b<<<NN, 128, 0, stream>>>(qb, kb, vb);

    // --- h0 = [x_struct | attn] @ Wo + bo (fused two-region A) ---
    gemm_mfma<1><<<dim3(1, MT), 256, 0, stream>>>(xb, 896, 128, vb, 128, 128, woT, h0b, 128, bo);

    // --- h1 = [h0 | x_sem] @ W1 (dual col tiles: halved A traffic) ---
    gemm_dual<<<dim3(2, MT), 256, 0, stream>>>(h0b, 128, 128, xb + 128, 896, 768,
                                               w1T, w1T + (size_t)128 * 896, h1b, h1b + 128, 512);

    // --- GAT layer 1 (fused softmax + gather, cooperative exp, 4-unroll) ---
    att_dots1_b<<<NN, 256, 0, stream>>>(h1b, as1, ad1, asrc, adst);
    agg1_f<<<NN, 256, 0, stream>>>(rowptr, esrc, asrc, adst, h1b, b1, o1b);

    // --- graph norm 1 + ELU (bf16 in place) ---
    fillk<<<4, 256, 0, stream>>>(msum, 0.f, 1024);
    colstat_b<<<(NN + 127) / 128, H1D, 0, stream>>>(o1b, msum, vsum, NN, 128);
    apply_norm_elu_b<<<(NN + 127) / 128, H1D, 0, stream>>>(o1b, msum, vsum, g1m, g1w, g1b, NN, 128);

    // --- GAT layer 2 ---
    gemm_mfma<1><<<dim3(1, MT), 256, 0, stream>>>(o1b, 512, 512, (const u16*)nullptr, 0, 0, w2T, h2b, 128, nullptr);
    att_dots2_b<<<NN, 128, 0, stream>>>(h2b, as2, ad2, asrc, adst);
    agg2_f<<<(NN + 3) / 4, 256, 0, stream>>>(rowptr, esrc, asrc, adst, h2b, b2, o2);

    // --- graph norm 2 + ELU + projection (fused) ---
    fillk<<<4, 256, 0, stream>>>(msum, 0.f, 1024);
    colstat<<<(NN + 127) / 128, HIDD, 0, stream>>>(o2, msum, vsum, NN, 128);
    norm2_proj<<<NN, 128, 0, stream>>>(o2, msum, vsum, g2m, g2w, g2b, Wn, bn, out);
}

// Round 7
// 652.790 us; speedup vs baseline: 1.1233x; 1.1233x over previous
//
#include <hip/hip_runtime.h>
#include <math.h>

#define NN 50000
#define NE 500000
#define EEDG 550000          // NE + NN self loops
#define SDIM 128             // STRUCT
#define MDIM 768             // SEM
#define HIDD 128             // HID
#define NHEADS 4
#define INDIM 896            // STRUCT + SEM
#define H1D 512              // HEADS*HID
#define SCAN_NB 196          // ceil(NN/256)
#define MP 50048             // NN padded to 128*391
#define MT 391               // row tiles of 128

typedef unsigned short u16;
typedef unsigned int u32;
typedef __attribute__((ext_vector_type(8))) short short8;
typedef __attribute__((ext_vector_type(4))) float f32x4;

// ---------------- bf16 helpers ----------------
__device__ __forceinline__ u16 f2bf(float f) {
    union { float f; u32 u; } v; v.f = f;
    u32 r = v.u + 0x7FFFu + ((v.u >> 16) & 1u);
    return (u16)(r >> 16);
}
__device__ __forceinline__ float bf2f(u16 h) {
    union { u32 u; float f; } v; v.u = ((u32)h) << 16;
    return v.f;
}

__device__ __forceinline__ void gl_lds16(const u16* g, u16* l) {
    __builtin_amdgcn_global_load_lds(
        (const __attribute__((address_space(1))) void*)g,
        (__attribute__((address_space(3))) void*)l, 16, 0, 0);
}

// ---------------- utility ----------------
__device__ __forceinline__ void edge_sd(const int* __restrict__ ei, int e, int& s, int& d) {
    if (e < NE) { s = ei[e]; d = ei[NE + e]; }
    else        { s = e - NE; d = e - NE; }
}

__global__ void fillk(float* __restrict__ p, float v, long count) {
    long i = (long)blockIdx.x * blockDim.x + threadIdx.x;
    long stride = (long)gridDim.x * blockDim.x;
    for (; i < count; i += stride) p[i] = v;
}

__global__ void fillk_i(int* __restrict__ p, int v, long count) {
    long i = (long)blockIdx.x * blockDim.x + threadIdx.x;
    long stride = (long)gridDim.x * blockDim.x;
    for (; i < count; i += stride) p[i] = v;
}

// ---------------- casts ----------------
__global__ __launch_bounds__(256) void cast_pad_x(const float4* __restrict__ x4, u16* __restrict__ xb) {
    const long total = (long)MP * 224;
    long i = (long)blockIdx.x * blockDim.x + threadIdx.x;
    long stride = (long)gridDim.x * blockDim.x;
    for (; i < total; i += stride) {
        int row = (int)(i / 224);
        int c4 = (int)(i - (long)row * 224);
        float4 v = make_float4(0.f, 0.f, 0.f, 0.f);
        if (row < NN) v = x4[(size_t)row * 224 + c4];
        short4 o;
        o.x = (short)f2bf(v.x); o.y = (short)f2bf(v.y);
        o.z = (short)f2bf(v.z); o.w = (short)f2bf(v.w);
        *(short4*)(xb + (size_t)row * 896 + c4 * 4) = o;
    }
}

// W (K x N f32, row-major) -> Wb (N x K bf16) transposed cast
__global__ __launch_bounds__(256) void cast_wT(const float* __restrict__ W, u16* __restrict__ Wb, int K, int N) {
    int k = blockIdx.x * 4 + (threadIdx.x >> 6);
    int n = blockIdx.y * 64 + (threadIdx.x & 63);
    if (k < K && n < N) Wb[(size_t)n * K + k] = f2bf(W[(size_t)k * N + n]);
}

// ---------------- CSR build ----------------
__global__ __launch_bounds__(256) void count_deg(const int* __restrict__ ei, int* __restrict__ deg) {
    int e = blockIdx.x * 256 + threadIdx.x;
    if (e >= EEDG) return;
    int d = e < NE ? ei[NE + e] : e - NE;
    atomicAdd(&deg[d], 1);
}

__global__ __launch_bounds__(256) void scan_bsum(const int* __restrict__ deg, int* __restrict__ part) {
    __shared__ int s[256];
    int t = threadIdx.x;
    int idx = blockIdx.x * 256 + t;
    s[t] = idx < NN ? deg[idx] : 0;
    __syncthreads();
    for (int off = 128; off; off >>= 1) {
        if (t < off) s[t] += s[t + off];
        __syncthreads();
    }
    if (t == 0) part[blockIdx.x] = s[0];
}

__global__ __launch_bounds__(256) void scan_part(int* __restrict__ part) {
    __shared__ int s[256];
    int t = threadIdx.x;
    int v = t < SCAN_NB ? part[t] : 0;
    s[t] = v;
    __syncthreads();
    for (int off = 1; off < 256; off <<= 1) {
        int x = t >= off ? s[t - off] : 0;
        __syncthreads();
        s[t] += x;
        __syncthreads();
    }
    if (t < SCAN_NB) part[t] = s[t] - v;   // exclusive
}

__global__ __launch_bounds__(256) void scan_write(const int* __restrict__ deg, const int* __restrict__ part,
                                                  int* __restrict__ rowptr) {
    __shared__ int s[256];
    int t = threadIdx.x;
    int idx = blockIdx.x * 256 + t;
    int v = idx < NN ? deg[idx] : 0;
    s[t] = v;
    __syncthreads();
    for (int off = 1; off < 256; off <<= 1) {
        int x = t >= off ? s[t - off] : 0;
        __syncthreads();
        s[t] += x;
        __syncthreads();
    }
    if (idx < NN) rowptr[idx] = part[blockIdx.x] + s[t] - v;
    if (idx == NN - 1) rowptr[NN] = EEDG;
}

__global__ __launch_bounds__(256) void fill_csr(const int* __restrict__ ei, const int* __restrict__ rowptr,
                                                int* __restrict__ cur, int* __restrict__ esrc,
                                                int* __restrict__ edst) {
    int e = blockIdx.x * 256 + threadIdx.x;
    if (e >= EEDG) return;
    int s, d;
    edge_sd(ei, e, s, d);
    int p = rowptr[d] + atomicAdd(&cur[d], 1);
    esrc[p] = s;
    edst[p] = d;
}

// ---------------- CSR-ordered per-edge softmax numerators ----------------
// exf[i*H + h] = exp(leaky(asrc[s,h] + adst[d,h])) for CSR slot i.
template<int H>
__global__ __launch_bounds__(256) void edge_exp(const int* __restrict__ esrc, const int* __restrict__ edst,
    const float* __restrict__ asrc, const float* __restrict__ adst, float* __restrict__ exf)
{
    int i = blockIdx.x * 256 + threadIdx.x;
    if (i >= EEDG) return;
    int s = esrc[i], d = edst[i];
    if (H == 4) {
        float4 as = *(const float4*)(asrc + s * 4);
        float4 ad = *(const float4*)(adst + d * 4);
        float4 o;
        float a;
        a = as.x + ad.x; a = a >= 0.f ? a : 0.2f * a; o.x = expf(a);
        a = as.y + ad.y; a = a >= 0.f ? a : 0.2f * a; o.y = expf(a);
        a = as.z + ad.z; a = a >= 0.f ? a : 0.2f * a; o.z = expf(a);
        a = as.w + ad.w; a = a >= 0.f ? a : 0.2f * a; o.w = expf(a);
        *(float4*)(exf + (size_t)i * 4) = o;
    } else {
        float a = asrc[s] + adst[d];
        a = a >= 0.f ? a : 0.2f * a;
        exf[i] = expf(a);
    }
}

// ---------------- MFMA bf16 GEMM body ----------------
template<int OUT_BF16>
__device__ __forceinline__ void gemm_body(
    u16* __restrict__ Asm, u16* __restrict__ Bsm,
    const u16* __restrict__ A1, int lda1, int K1,
    const u16* __restrict__ A2, int lda2, int K2,
    const u16* __restrict__ Bw,
    void* __restrict__ Cout, int ldc,
    const float* __restrict__ bias, int row0, int col0)
{
    const int tid = threadIdx.x;
    const int wave = tid >> 6, lane = tid & 63;
    const int wr = wave >> 1, wc = wave & 1;
    const int K = K1 + K2;
    const int srow = tid >> 2;
    const int skp = (tid & 3) * 8;
    const int l15 = lane & 15, l4 = lane >> 4;

    f32x4 acc[4][4];
    #pragma unroll
    for (int i = 0; i < 4; ++i)
        #pragma unroll
        for (int j = 0; j < 4; ++j)
            acc[i][j] = (f32x4){0.f, 0.f, 0.f, 0.f};

    for (int k0 = 0; k0 < K; k0 += 32) {
        const u16* Ab; int la; int kk;
        if (k0 < K1) { Ab = A1; la = lda1; kk = k0; }
        else         { Ab = A2; la = lda2; kk = k0 - K1; }
        gl_lds16(Ab + (size_t)(row0 + srow) * la + kk + skp,      Asm + srow * 32 + skp);
        gl_lds16(Ab + (size_t)(row0 + srow + 64) * la + kk + skp, Asm + (srow + 64) * 32 + skp);
        gl_lds16(Bw + (size_t)(col0 + srow) * K + k0 + skp,       Bsm + srow * 32 + skp);
        gl_lds16(Bw + (size_t)(col0 + srow + 64) * K + k0 + skp,  Bsm + (srow + 64) * 32 + skp);
        __syncthreads();
        short8 af[4], bfr[4];
        #pragma unroll
        for (int m = 0; m < 4; ++m)
            af[m] = *(const short8*)(Asm + (wr * 64 + m * 16 + l15) * 32 + l4 * 8);
        #pragma unroll
        for (int n = 0; n < 4; ++n)
            bfr[n] = *(const short8*)(Bsm + (wc * 64 + n * 16 + l15) * 32 + l4 * 8);
        #pragma unroll
        for (int m = 0; m < 4; ++m)
            #pragma unroll
            for (int n = 0; n < 4; ++n)
                acc[m][n] = __builtin_amdgcn_mfma_f32_16x16x32_bf16(af[m], bfr[n], acc[m][n], 0, 0, 0);
        __syncthreads();
    }
    #pragma unroll
    for (int m = 0; m < 4; ++m) {
        int r = row0 + wr * 64 + m * 16 + l4 * 4;
        #pragma unroll
        for (int n = 0; n < 4; ++n) {
            int c = col0 + wc * 64 + n * 16 + l15;
            float bv = bias ? bias[c] : 0.f;
            #pragma unroll
            for (int q = 0; q < 4; ++q) {
                float v = acc[m][n][q] + bv;
                if (OUT_BF16) ((u16*)Cout)[(size_t)(r + q) * ldc + c] = f2bf(v);
                else          ((float*)Cout)[(size_t)(r + q) * ldc + c] = v;
            }
        }
    }
}

template<int OUT_BF16>
__global__ __launch_bounds__(256) void gemm_mfma(
    const u16* __restrict__ A1, int lda1, int K1,
    const u16* __restrict__ A2, int lda2, int K2,
    const u16* __restrict__ Bw,
    void* __restrict__ Cout, int ldc,
    const float* __restrict__ bias)
{
    __shared__ u16 Asm[128 * 32];
    __shared__ u16 Bsm[128 * 32];
    gemm_body<OUT_BF16>(Asm, Bsm, A1, lda1, K1, A2, lda2, K2, Bw, Cout, ldc, bias,
                        blockIdx.y * 128, blockIdx.x * 128);
}

// fused Q|K|V: blockIdx.x selects which product
__global__ __launch_bounds__(256) void gemm_qkv(
    const u16* __restrict__ xb,
    const u16* __restrict__ wqT, const u16* __restrict__ wkT, const u16* __restrict__ wvT,
    u16* __restrict__ qb, u16* __restrict__ kb, u16* __restrict__ vb)
{
    __shared__ u16 Asm[128 * 32];
    __shared__ u16 Bsm[128 * 32];
    const u16* A; const u16* B; int K; u16* C;
    if (blockIdx.x == 0)      { A = xb;       B = wqT; K = 128; C = qb; }
    else if (blockIdx.x == 1) { A = xb + 128; B = wkT; K = 768; C = kb; }
    else                      { A = xb + 128; B = wvT; K = 768; C = vb; }
    gemm_body<1>(Asm, Bsm, A, 896, K, (const u16*)nullptr, 0, 0, B, C, 128, nullptr,
                 blockIdx.y * 128, 0);
}

// ---------------- node cross-attention (bf16): V *= sigmoid(dot(Q,K)) ----------------
__global__ __launch_bounds__(128) void node_attn_b(const u16* __restrict__ Q,
                                                   const u16* __restrict__ K,
                                                   u16* __restrict__ V)
{
    int nd = blockIdx.x;
    int t = threadIdx.x;
    size_t base = (size_t)nd * HIDD;
    float p = bf2f(Q[base + t]) * bf2f(K[base + t]);
    #pragma unroll
    for (int off = 32; off; off >>= 1) p += __shfl_down(p, off);
    __shared__ float sm[2];
    if ((t & 63) == 0) sm[t >> 6] = p;
    __syncthreads();
    float s = sm[0] + sm[1];
    float sig = 1.f / (1.f + expf(-s));
    V[base + t] = f2bf(bf2f(V[base + t]) * sig);
}

// ---------------- GAT attention-coefficient dots ----------------
__global__ __launch_bounds__(256) void att_dots1_b(const u16* __restrict__ h1,
    const float* __restrict__ asv, const float* __restrict__ adv,
    float* __restrict__ a_src, float* __restrict__ a_dst)
{
    int nd = blockIdx.x;
    int t = threadIdx.x;
    int w = t >> 6, l = t & 63;
    const u16* hr = h1 + (size_t)nd * H1D + w * HIDD;
    const float* sv = asv + w * HIDD;
    const float* dv = adv + w * HIDD;
    float h0v = bf2f(hr[l]), h1v = bf2f(hr[l + 64]);
    float ps = h0v * sv[l] + h1v * sv[l + 64];
    float pd = h0v * dv[l] + h1v * dv[l + 64];
    #pragma unroll
    for (int off = 32; off; off >>= 1) {
        ps += __shfl_down(ps, off);
        pd += __shfl_down(pd, off);
    }
    if (l == 0) { a_src[nd * NHEADS + w] = ps; a_dst[nd * NHEADS + w] = pd; }
}

__global__ __launch_bounds__(128) void att_dots2_b(const u16* __restrict__ h2,
    const float* __restrict__ sv, const float* __restrict__ dv,
    float* __restrict__ a_src, float* __restrict__ a_dst)
{
    int nd = blockIdx.x;
    int t = threadIdx.x;
    float hv = bf2f(h2[(size_t)nd * HIDD + t]);
    float ps = hv * sv[t], pd = hv * dv[t];
    #pragma unroll
    for (int off = 32; off; off >>= 1) {
        ps += __shfl_down(ps, off);
        pd += __shfl_down(pd, off);
    }
    __shared__ float sm[4];
    if ((t & 63) == 0) { sm[t >> 6] = ps; sm[2 + (t >> 6)] = pd; }
    __syncthreads();
    if (t == 0) { a_src[nd] = sm[0] + sm[1]; a_dst[nd] = sm[2] + sm[3]; }
}

// ---------------- fused softmax + gather aggregation (barrier-free) ----------------
// layer 1: block per dst, 256 thr x 2 cols; per-edge exp precomputed in exf
// (CSR order, scalar-broadcast reads), gather 4-unrolled for MLP.
__global__ __launch_bounds__(256) void agg1_f(const int* __restrict__ rowptr, const int* __restrict__ esrc,
    const float* __restrict__ exf,
    const u16* __restrict__ h1b, const float* __restrict__ bias, u16* __restrict__ o1b)
{
    int d = blockIdx.x;
    int t = threadIdx.x;
    int c0 = t * 2;
    int h = t >> 6;
    int beg = rowptr[d], end = rowptr[d + 1];
    float n0 = 0.f, n1 = 0.f, den = 0.f;
    int i = beg;
    for (; i + 3 < end; i += 4) {
        int sA = esrc[i], sB = esrc[i + 1], sC = esrc[i + 2], sD = esrc[i + 3];
        float aA = exf[(size_t)i * 4 + h],       aB = exf[(size_t)(i + 1) * 4 + h];
        float aC = exf[(size_t)(i + 2) * 4 + h], aD = exf[(size_t)(i + 3) * 4 + h];
        u32 pA = *(const u32*)(h1b + (size_t)sA * H1D + c0);
        u32 pB = *(const u32*)(h1b + (size_t)sB * H1D + c0);
        u32 pC = *(const u32*)(h1b + (size_t)sC * H1D + c0);
        u32 pD = *(const u32*)(h1b + (size_t)sD * H1D + c0);
        den += (aA + aB) + (aC + aD);
        n0 = fmaf(bf2f((u16)pA), aA, n0);
        n1 = fmaf(bf2f((u16)(pA >> 16)), aA, n1);
        n0 = fmaf(bf2f((u16)pB), aB, n0);
        n1 = fmaf(bf2f((u16)(pB >> 16)), aB, n1);
        n0 = fmaf(bf2f((u16)pC), aC, n0);
        n1 = fmaf(bf2f((u16)(pC >> 16)), aC, n1);
        n0 = fmaf(bf2f((u16)pD), aD, n0);
        n1 = fmaf(bf2f((u16)(pD >> 16)), aD, n1);
    }
    for (; i < end; ++i) {
        int sA = esrc[i];
        float aA = exf[(size_t)i * 4 + h];
        u32 pA = *(const u32*)(h1b + (size_t)sA * H1D + c0);
        den += aA;
        n0 = fmaf(bf2f((u16)pA), aA, n0);
        n1 = fmaf(bf2f((u16)(pA >> 16)), aA, n1);
    }
    float invd = 1.f / (den + 1e-16f);
    float a0o = n0 * invd + bias[c0];
    float a1o = n1 * invd + bias[c0 + 1];
    u32 o = (u32)f2bf(a0o) | ((u32)f2bf(a1o) << 16);
    *(u32*)(o1b + (size_t)d * H1D + c0) = o;
}

// layer 2: wave per dst (4/block), 64 lanes x 2 cols, exf2 broadcast reads.
__global__ __launch_bounds__(256) void agg2_f(const int* __restrict__ rowptr, const int* __restrict__ esrc,
    const float* __restrict__ exf,
    const u16* __restrict__ h2b, const float* __restrict__ bias, float* __restrict__ o2)
{
    int w = threadIdx.x >> 6, l = threadIdx.x & 63;
    int d = blockIdx.x * 4 + w;
    if (d >= NN) return;
    int c0 = l * 2;
    int beg = rowptr[d], end = rowptr[d + 1];
    float n0 = 0.f, n1 = 0.f, den = 0.f;
    int i = beg;
    for (; i + 3 < end; i += 4) {
        int sA = esrc[i], sB = esrc[i + 1], sC = esrc[i + 2], sD = esrc[i + 3];
        float aA = exf[i], aB = exf[i + 1], aC = exf[i + 2], aD = exf[i + 3];
        u32 pA = *(const u32*)(h2b + (size_t)sA * HIDD + c0);
        u32 pB = *(const u32*)(h2b + (size_t)sB * HIDD + c0);
        u32 pC = *(const u32*)(h2b + (size_t)sC * HIDD + c0);
        u32 pD = *(const u32*)(h2b + (size_t)sD * HIDD + c0);
        den += (aA + aB) + (aC + aD);
        n0 = fmaf(bf2f((u16)pA), aA, n0);
        n1 = fmaf(bf2f((u16)(pA >> 16)), aA, n1);
        n0 = fmaf(bf2f((u16)pB), aB, n0);
        n1 = fmaf(bf2f((u16)(pB >> 16)), aB, n1);
        n0 = fmaf(bf2f((u16)pC), aC, n0);
        n1 = fmaf(bf2f((u16)(pC >> 16)), aC, n1);
        n0 = fmaf(bf2f((u16)pD), aD, n0);
        n1 = fmaf(bf2f((u16)(pD >> 16)), aD, n1);
    }
    for (; i < end; ++i) {
        int sA = esrc[i];
        float aA = exf[i];
        u32 pA = *(const u32*)(h2b + (size_t)sA * HIDD + c0);
        den += aA;
        n0 = fmaf(bf2f((u16)pA), aA, n0);
        n1 = fmaf(bf2f((u16)(pA >> 16)), aA, n1);
    }
    float invd = 1.f / (den + 1e-16f);
    o2[(size_t)d * HIDD + c0]     = n0 * invd + bias[c0];
    o2[(size_t)d * HIDD + c0 + 1] = n1 * invd + bias[c0 + 1];
}

// ---------------- graph norm ----------------
__global__ void colstat_b(const u16* __restrict__ x, float* __restrict__ msum,
                          float* __restrict__ vsum, int n, int rpb)
{
    int C = blockDim.x;
    int c = threadIdx.x;
    int r0 = blockIdx.x * rpb;
    int r1 = min(n, r0 + rpb);
    float s = 0.f, s2 = 0.f;
    for (int r = r0; r < r1; ++r) {
        float v = bf2f(x[(size_t)r * C + c]);
        s += v;
        s2 += v * v;
    }
    atomicAdd(&msum[c], s);
    atomicAdd(&vsum[c], s2);
}

__global__ void apply_norm_elu_b(u16* __restrict__ x, const float* __restrict__ msum,
                                 const float* __restrict__ vsum, const float* __restrict__ ms,
                                 const float* __restrict__ w, const float* __restrict__ b,
                                 int n, int rpb)
{
    int C = blockDim.x;
    int c = threadIdx.x;
    const float invn = 1.f / (float)NN;
    float mean = msum[c] * invn;
    float sub = mean * ms[c];
    float var = vsum[c] * invn - 2.f * sub * mean + sub * sub;
    float inv = rsqrtf(var + 1e-5f);
    float wc = w[c] * inv, bc = b[c];
    int r0 = blockIdx.x * rpb;
    int r1 = min(n, r0 + rpb);
    for (int r = r0; r < r1; ++r) {
        float v = (bf2f(x[(size_t)r * C + c]) - sub) * wc + bc;
        v = v > 0.f ? v : expm1f(v);
        x[(size_t)r * C + c] = f2bf(v);
    }
}

__global__ void colstat(const float* __restrict__ x, float* __restrict__ msum,
                        float* __restrict__ vsum, int n, int rpb)
{
    int C = blockDim.x;
    int c = threadIdx.x;
    int r0 = blockIdx.x * rpb;
    int r1 = min(n, r0 + rpb);
    float s = 0.f, s2 = 0.f;
    for (int r = r0; r < r1; ++r) {
        float v = x[(size_t)r * C + c];
        s += v;
        s2 += v * v;
    }
    atomicAdd(&msum[c], s);
    atomicAdd(&vsum[c], s2);
}

// ---------------- fused norm2 + ELU + final projection ----------------
__global__ __launch_bounds__(128) void norm2_proj(const float* __restrict__ o2,
    const float* __restrict__ msum, const float* __restrict__ vsum,
    const float* __restrict__ ms, const float* __restrict__ w, const float* __restrict__ b,
    const float* __restrict__ Wn, const float* __restrict__ bn, float* __restrict__ out)
{
    int nd = blockIdx.x;
    int t = threadIdx.x;
    const float invn = 1.f / (float)NN;
    float mean = msum[t] * invn;
    float sub = mean * ms[t];
    float var = vsum[t] * invn - 2.f * sub * mean + sub * sub;
    float inv = rsqrtf(var + 1e-5f);
    float v = (o2[(size_t)nd * HIDD + t] - sub) * w[t] * inv + b[t];
    v = v > 0.f ? v : expm1f(v);
    float p0 = v * Wn[t * 2], p1 = v * Wn[t * 2 + 1];
    #pragma unroll
    for (int off = 32; off; off >>= 1) {
        p0 += __shfl_down(p0, off);
        p1 += __shfl_down(p1, off);
    }
    __shared__ float sm[4];
    if ((t & 63) == 0) { sm[t >> 6] = p0; sm[2 + (t >> 6)] = p1; }
    __syncthreads();
    if (t == 0) {
        out[nd * 2 + 0] = sm[0] + sm[1] + bn[0];
        out[nd * 2 + 1] = sm[2] + sm[3] + bn[1];
    }
}

// ---------------- host launch ----------------
extern "C" void kernel_launch(void* const* d_in, const int* in_sizes, int n_in,
                              void* d_out, int out_size, void* d_ws, size_t ws_size,
                              hipStream_t stream)
{
    const float* x   = (const float*)d_in[0];
    const int*   ei  = (const int*)d_in[1];
    const float* Wq  = (const float*)d_in[2];
    const float* Wk  = (const float*)d_in[3];
    const float* Wv  = (const float*)d_in[4];
    const float* Wo  = (const float*)d_in[5];
    const float* bo  = (const float*)d_in[6];
    const float* W1  = (const float*)d_in[7];
    const float* as1 = (const float*)d_in[8];
    const float* ad1 = (const float*)d_in[9];
    const float* b1  = (const float*)d_in[10];
    const float* g1w = (const float*)d_in[11];
    const float* g1b = (const float*)d_in[12];
    const float* g1m = (const float*)d_in[13];
    const float* W2  = (const float*)d_in[14];
    const float* as2 = (const float*)d_in[15];
    const float* ad2 = (const float*)d_in[16];
    const float* b2  = (const float*)d_in[17];
    const float* g2w = (const float*)d_in[18];
    const float* g2b = (const float*)d_in[19];
    const float* g2m = (const float*)d_in[20];
    const float* Wn  = (const float*)d_in[21];
    const float* bn  = (const float*)d_in[22];
    float* out = (float*)d_out;

    // ---- workspace layout ----
    u16* usw = (u16*)d_ws;
    size_t uo = 0;
    u16* xb  = usw + uo; uo += (size_t)MP * 896;
    u16* h1b = usw + uo; uo += (size_t)MP * 512;
    u16* qb  = usw + uo; uo += (size_t)MP * 128;
    u16* kb  = usw + uo; uo += (size_t)MP * 128;   // later h2b
    u16* vb  = usw + uo; uo += (size_t)MP * 128;
    u16* o1b = usw + uo; uo += (size_t)MP * 512;
    u16* wqT = usw + uo; uo += 128 * 128;
    u16* wkT = usw + uo; uo += 128 * 768;
    u16* wvT = usw + uo; uo += 128 * 768;
    u16* woT = usw + uo; uo += 128 * 256;
    u16* w1T = usw + uo; uo += 512 * 896;
    u16* w2T = usw + uo; uo += 128 * 512;
    float* fws = (float*)(usw + uo);
    size_t fo = 0;
    float* asrc = fws + fo; fo += NN * NHEADS;
    float* adst = fws + fo; fo += NN * NHEADS;
    float* exf  = fws + fo; fo += (size_t)EEDG * NHEADS;   // layer2 reuses front
    float* msum = fws + fo; fo += 512;
    float* vsum = fws + fo; fo += 512;
    int* iws = (int*)(fws + fo);
    size_t io = 0;
    int* rowptr = iws + io; io += NN + 1;
    int* degcur = iws + io; io += 2 * NN;     // [deg | cur] zeroed together
    int* esrc   = iws + io; io += EEDG;
    int* edst   = iws + io; io += EEDG;
    int* spart  = iws + io; io += 256;
    int* cur    = degcur + NN;
    // aliases: xb region free after h1 GEMM
    float* o2  = (float*)xb;
    u16* h0b = qb;   // reuse q after node_attn
    u16* h2b = kb;   // reuse k after node_attn

    const int EB = (EEDG + 255) / 256;

    // --- weight casts (transposed to N x K) ---
    cast_wT<<<dim3(32, 2),   256, 0, stream>>>(Wq, wqT, 128, 128);
    cast_wT<<<dim3(192, 2),  256, 0, stream>>>(Wk, wkT, 768, 128);
    cast_wT<<<dim3(192, 2),  256, 0, stream>>>(Wv, wvT, 768, 128);
    cast_wT<<<dim3(64, 2),   256, 0, stream>>>(Wo, woT, 256, 128);
    cast_wT<<<dim3(224, 8),  256, 0, stream>>>(W1, w1T, 896, 512);
    cast_wT<<<dim3(128, 2),  256, 0, stream>>>(W2, w2T, 512, 128);
    cast_pad_x<<<8192, 256, 0, stream>>>((const float4*)x, xb);

    // --- CSR build (esrc + edst) ---
    fillk_i<<<392, 256, 0, stream>>>(degcur, 0, 2 * NN);
    count_deg<<<EB, 256, 0, stream>>>(ei, degcur);
    scan_bsum<<<SCAN_NB, 256, 0, stream>>>(degcur, spart);
    scan_part<<<1, 256, 0, stream>>>(spart);
    scan_write<<<SCAN_NB, 256, 0, stream>>>(degcur, spart, rowptr);
    fill_csr<<<EB, 256, 0, stream>>>(ei, rowptr, cur, esrc, edst);

    // --- cross attention: Q|K|V in one dispatch, then gate ---
    gemm_qkv<<<dim3(3, MT), 256, 0, stream>>>(xb, wqT, wkT, wvT, qb, kb, vb);
    node_attn_b<<<NN, 128, 0, stream>>>(qb, kb, vb);

    // --- h0 = [x_struct | attn] @ Wo + bo (fused two-region A) ---
    gemm_mfma<1><<<dim3(1, MT), 256, 0, stream>>>(xb, 896, 128, vb, 128, 128, woT, h0b, 128, bo);

    // --- h1 = [h0 | x_sem] @ W1 (fused two-region A) ---
    gemm_mfma<1><<<dim3(4, MT), 256, 0, stream>>>(h0b, 128, 128, xb + 128, 896, 768, w1T, h1b, 512, nullptr);

    // --- GAT layer 1: dots -> CSR-ordered edge exp -> barrier-free gather ---
    att_dots1_b<<<NN, 256, 0, stream>>>(h1b, as1, ad1, asrc, adst);
    edge_exp<NHEADS><<<EB, 256, 0, stream>>>(esrc, edst, asrc, adst, exf);
    agg1_f<<<NN, 256, 0, stream>>>(rowptr, esrc, exf, h1b, b1, o1b);

    // --- graph norm 1 + ELU (bf16 in place) ---
    fillk<<<4, 256, 0, stream>>>(msum, 0.f, 1024);
    colstat_b<<<(NN + 127) / 128, H1D, 0, stream>>>(o1b, msum, vsum, NN, 128);
    apply_norm_elu_b<<<(NN + 127) / 128, H1D, 0, stream>>>(o1b, msum, vsum, g1m, g1w, g1b, NN, 128);

    // --- GAT layer 2 ---
    gemm_mfma<1><<<dim3(1, MT), 256, 0, stream>>>(o1b, 512, 512, (const u16*)nullptr, 0, 0, w2T, h2b, 128, nullptr);
    att_dots2_b<<<NN, 128, 0, stream>>>(h2b, as2, ad2, asrc, adst);
    edge_exp<1><<<EB, 256, 0, stream>>>(esrc, edst, asrc, adst, exf);
    agg2_f<<<(NN + 3) / 4, 256, 0, stream>>>(rowptr, esrc, exf, h2b, b2, o2);

    // --- graph norm 2 + ELU + projection (fused) ---
    fillk<<<4, 256, 0, stream>>>(msum, 0.f, 1024);
    colstat<<<(NN + 127) / 128, HIDD, 0, stream>>>(o2, msum, vsum, NN, 128);
    norm2_proj<<<NN, 128, 0, stream>>>(o2, msum, vsum, g2m, g2w, g2b, Wn, bn, out);
}

// Round 8
// 635.273 us; speedup vs baseline: 1.1542x; 1.0276x over previous
//
#include <hip/hip_runtime.h>
#include <math.h>

#define NN 50000
#define NE 500000
#define EEDG 550000          // NE + NN self loops
#define SDIM 128             // STRUCT
#define MDIM 768             // SEM
#define HIDD 128             // HID
#define NHEADS 4
#define INDIM 896            // STRUCT + SEM
#define H1D 512              // HEADS*HID
#define SCAN_NB 196          // ceil(NN/256)
#define MP 50048             // NN padded to 128*391
#define MT 391               // row tiles of 128

typedef unsigned short u16;
typedef unsigned int u32;
typedef __attribute__((ext_vector_type(8))) short short8;
typedef __attribute__((ext_vector_type(4))) float f32x4;

// ---------------- bf16 helpers ----------------
__device__ __forceinline__ u16 f2bf(float f) {
    union { float f; u32 u; } v; v.f = f;
    u32 r = v.u + 0x7FFFu + ((v.u >> 16) & 1u);
    return (u16)(r >> 16);
}
__device__ __forceinline__ float bf2f(u16 h) {
    union { u32 u; float f; } v; v.u = ((u32)h) << 16;
    return v.f;
}

__device__ __forceinline__ void gl_lds16(const u16* g, u16* l) {
    __builtin_amdgcn_global_load_lds(
        (const __attribute__((address_space(1))) void*)g,
        (__attribute__((address_space(3))) void*)l, 16, 0, 0);
}

// ---------------- utility ----------------
__device__ __forceinline__ void edge_sd(const int* __restrict__ ei, int e, int& s, int& d) {
    if (e < NE) { s = ei[e]; d = ei[NE + e]; }
    else        { s = e - NE; d = e - NE; }
}

// ---------------- fused init: all weight casts (transposed) + zero fills ----------------
// linear work: [Wq|Wk|Wv|Wo|W1|W2 casts][degcur+cur zero][msum/vsum zero]
__global__ __launch_bounds__(256) void cast_weights(
    const float* __restrict__ Wq, const float* __restrict__ Wk, const float* __restrict__ Wv,
    const float* __restrict__ Wo, const float* __restrict__ W1, const float* __restrict__ W2,
    u16* __restrict__ wqT, u16* __restrict__ wkT, u16* __restrict__ wvT,
    u16* __restrict__ woT, u16* __restrict__ w1T, u16* __restrict__ w2T,
    int* __restrict__ degcur, float* __restrict__ msum)
{
    const int SQ = 128 * 128, SK = 128 * 768, SV = 128 * 768,
              SO = 256 * 128, S1 = 896 * 512, S2 = 512 * 128;
    long i = (long)blockIdx.x * 256 + threadIdx.x;
    long w = i;
    if (w < SQ) { int n = (int)(w / 128), k = (int)(w % 128); wqT[w] = f2bf(Wq[(size_t)k * 128 + n]); return; }
    w -= SQ;
    if (w < SK) { int n = (int)(w / 768), k = (int)(w % 768); wkT[w] = f2bf(Wk[(size_t)k * 128 + n]); return; }
    w -= SK;
    if (w < SV) { int n = (int)(w / 768), k = (int)(w % 768); wvT[w] = f2bf(Wv[(size_t)k * 128 + n]); return; }
    w -= SV;
    if (w < SO) { int n = (int)(w / 256), k = (int)(w % 256); woT[w] = f2bf(Wo[(size_t)k * 128 + n]); return; }
    w -= SO;
    if (w < S1) { int n = (int)(w / 896), k = (int)(w % 896); w1T[w] = f2bf(W1[(size_t)k * 512 + n]); return; }
    w -= S1;
    if (w < S2) { int n = (int)(w / 512), k = (int)(w % 512); w2T[w] = f2bf(W2[(size_t)k * 128 + n]); return; }
    w -= S2;
    if (w < 2 * NN) { degcur[w] = 0; return; }
    w -= 2 * NN;
    if (w < 1024) msum[w] = 0.f;
}

// ---------------- x cast + pad ----------------
__global__ __launch_bounds__(256) void cast_pad_x(const float4* __restrict__ x4, u16* __restrict__ xb) {
    const long total = (long)MP * 224;
    long i = (long)blockIdx.x * blockDim.x + threadIdx.x;
    long stride = (long)gridDim.x * blockDim.x;
    for (; i < total; i += stride) {
        int row = (int)(i / 224);
        int c4 = (int)(i - (long)row * 224);
        float4 v = make_float4(0.f, 0.f, 0.f, 0.f);
        if (row < NN) v = x4[(size_t)row * 224 + c4];
        short4 o;
        o.x = (short)f2bf(v.x); o.y = (short)f2bf(v.y);
        o.z = (short)f2bf(v.z); o.w = (short)f2bf(v.w);
        *(short4*)(xb + (size_t)row * 896 + c4 * 4) = o;
    }
}

// ---------------- CSR build ----------------
__global__ __launch_bounds__(256) void count_deg(const int* __restrict__ ei, int* __restrict__ deg) {
    int e = blockIdx.x * 256 + threadIdx.x;
    if (e >= EEDG) return;
    int d = e < NE ? ei[NE + e] : e - NE;
    atomicAdd(&deg[d], 1);
}

__global__ __launch_bounds__(256) void scan_bsum(const int* __restrict__ deg, int* __restrict__ part) {
    __shared__ int s[256];
    int t = threadIdx.x;
    int idx = blockIdx.x * 256 + t;
    s[t] = idx < NN ? deg[idx] : 0;
    __syncthreads();
    for (int off = 128; off; off >>= 1) {
        if (t < off) s[t] += s[t + off];
        __syncthreads();
    }
    if (t == 0) part[blockIdx.x] = s[0];
}

__global__ __launch_bounds__(256) void scan_part(int* __restrict__ part) {
    __shared__ int s[256];
    int t = threadIdx.x;
    int v = t < SCAN_NB ? part[t] : 0;
    s[t] = v;
    __syncthreads();
    for (int off = 1; off < 256; off <<= 1) {
        int x = t >= off ? s[t - off] : 0;
        __syncthreads();
        s[t] += x;
        __syncthreads();
    }
    if (t < SCAN_NB) part[t] = s[t] - v;   // exclusive
}

__global__ __launch_bounds__(256) void scan_write(const int* __restrict__ deg, const int* __restrict__ part,
                                                  int* __restrict__ rowptr) {
    __shared__ int s[256];
    int t = threadIdx.x;
    int idx = blockIdx.x * 256 + t;
    int v = idx < NN ? deg[idx] : 0;
    s[t] = v;
    __syncthreads();
    for (int off = 1; off < 256; off <<= 1) {
        int x = t >= off ? s[t - off] : 0;
        __syncthreads();
        s[t] += x;
        __syncthreads();
    }
    if (idx < NN) rowptr[idx] = part[blockIdx.x] + s[t] - v;
    if (idx == NN - 1) rowptr[NN] = EEDG;
}

__global__ __launch_bounds__(256) void fill_csr(const int* __restrict__ ei, const int* __restrict__ rowptr,
                                                int* __restrict__ cur, int* __restrict__ esrc,
                                                int* __restrict__ edst) {
    int e = blockIdx.x * 256 + threadIdx.x;
    if (e >= EEDG) return;
    int s, d;
    edge_sd(ei, e, s, d);
    int p = rowptr[d] + atomicAdd(&cur[d], 1);
    esrc[p] = s;
    edst[p] = d;
}

// ---------------- CSR-ordered per-edge softmax numerators ----------------
template<int H>
__global__ __launch_bounds__(256) void edge_exp(const int* __restrict__ esrc, const int* __restrict__ edst,
    const float* __restrict__ asrc, const float* __restrict__ adst, float* __restrict__ exf)
{
    int i = blockIdx.x * 256 + threadIdx.x;
    if (i >= EEDG) return;
    int s = esrc[i], d = edst[i];
    if (H == 4) {
        float4 as = *(const float4*)(asrc + s * 4);
        float4 ad = *(const float4*)(adst + d * 4);
        float4 o;
        float a;
        a = as.x + ad.x; a = a >= 0.f ? a : 0.2f * a; o.x = expf(a);
        a = as.y + ad.y; a = a >= 0.f ? a : 0.2f * a; o.y = expf(a);
        a = as.z + ad.z; a = a >= 0.f ? a : 0.2f * a; o.z = expf(a);
        a = as.w + ad.w; a = a >= 0.f ? a : 0.2f * a; o.w = expf(a);
        *(float4*)(exf + (size_t)i * 4) = o;
    } else {
        float a = asrc[s] + adst[d];
        a = a >= 0.f ? a : 0.2f * a;
        exf[i] = expf(a);
    }
}

// ---------------- MFMA bf16 GEMM body (optional fused att-dot epilogue) ----------------
// DOTS: also compute aout_s[r*DH+head] = sum_c acc[r,c]*dvs[head*128+c] (and dvd).
template<int OUT_BF16, int DOTS, int DH>
__device__ __forceinline__ void gemm_body(
    u16* __restrict__ Asm, u16* __restrict__ Bsm,
    const u16* __restrict__ A1, int lda1, int K1,
    const u16* __restrict__ A2, int lda2, int K2,
    const u16* __restrict__ Bw,
    void* __restrict__ Cout, int ldc,
    const float* __restrict__ bias, int row0, int col0,
    const float* __restrict__ dvs, const float* __restrict__ dvd,
    float* __restrict__ aout_s, float* __restrict__ aout_d)
{
    const int tid = threadIdx.x;
    const int wave = tid >> 6, lane = tid & 63;
    const int wr = wave >> 1, wc = wave & 1;
    const int K = K1 + K2;
    const int srow = tid >> 2;
    const int skp = (tid & 3) * 8;
    const int l15 = lane & 15, l4 = lane >> 4;

    f32x4 acc[4][4];
    #pragma unroll
    for (int i = 0; i < 4; ++i)
        #pragma unroll
        for (int j = 0; j < 4; ++j)
            acc[i][j] = (f32x4){0.f, 0.f, 0.f, 0.f};

    for (int k0 = 0; k0 < K; k0 += 32) {
        const u16* Ab; int la; int kk;
        if (k0 < K1) { Ab = A1; la = lda1; kk = k0; }
        else         { Ab = A2; la = lda2; kk = k0 - K1; }
        gl_lds16(Ab + (size_t)(row0 + srow) * la + kk + skp,      Asm + srow * 32 + skp);
        gl_lds16(Ab + (size_t)(row0 + srow + 64) * la + kk + skp, Asm + (srow + 64) * 32 + skp);
        gl_lds16(Bw + (size_t)(col0 + srow) * K + k0 + skp,       Bsm + srow * 32 + skp);
        gl_lds16(Bw + (size_t)(col0 + srow + 64) * K + k0 + skp,  Bsm + (srow + 64) * 32 + skp);
        __syncthreads();
        short8 af[4], bfr[4];
        #pragma unroll
        for (int m = 0; m < 4; ++m)
            af[m] = *(const short8*)(Asm + (wr * 64 + m * 16 + l15) * 32 + l4 * 8);
        #pragma unroll
        for (int n = 0; n < 4; ++n)
            bfr[n] = *(const short8*)(Bsm + (wc * 64 + n * 16 + l15) * 32 + l4 * 8);
        #pragma unroll
        for (int m = 0; m < 4; ++m)
            #pragma unroll
            for (int n = 0; n < 4; ++n)
                acc[m][n] = __builtin_amdgcn_mfma_f32_16x16x32_bf16(af[m], bfr[n], acc[m][n], 0, 0, 0);
        __syncthreads();
    }
    #pragma unroll
    for (int m = 0; m < 4; ++m) {
        int r = row0 + wr * 64 + m * 16 + l4 * 4;
        #pragma unroll
        for (int n = 0; n < 4; ++n) {
            int c = col0 + wc * 64 + n * 16 + l15;
            float bv = bias ? bias[c] : 0.f;
            #pragma unroll
            for (int q = 0; q < 4; ++q) {
                float v = acc[m][n][q] + bv;
                if (OUT_BF16) ((u16*)Cout)[(size_t)(r + q) * ldc + c] = f2bf(v);
                else          ((float*)Cout)[(size_t)(r + q) * ldc + c] = v;
            }
        }
    }
    if (DOTS) {
        const int head = (DH == 1) ? 0 : (col0 >> 7);
        const float* svp = dvs + head * 128;
        const float* dvp = dvd + head * 128;
        float sv[4], dv[4];
        #pragma unroll
        for (int n = 0; n < 4; ++n) {
            int cc = wc * 64 + n * 16 + l15;
            sv[n] = svp[cc];
            dv[n] = dvp[cc];
        }
        __shared__ float red[128][2][2];
        #pragma unroll
        for (int m = 0; m < 4; ++m) {
            #pragma unroll
            for (int q = 0; q < 4; ++q) {
                float ps = 0.f, pd = 0.f;
                #pragma unroll
                for (int n = 0; n < 4; ++n) {
                    ps = fmaf(acc[m][n][q], sv[n], ps);
                    pd = fmaf(acc[m][n][q], dv[n], pd);
                }
                #pragma unroll
                for (int off = 1; off < 16; off <<= 1) {
                    ps += __shfl_xor(ps, off);
                    pd += __shfl_xor(pd, off);
                }
                if (l15 == 0) {
                    int lr = wr * 64 + m * 16 + l4 * 4 + q;
                    red[lr][wc][0] = ps;
                    red[lr][wc][1] = pd;
                }
            }
        }
        __syncthreads();
        if (tid < 128) {
            int r = row0 + tid;
            aout_s[(size_t)r * DH + head] = red[tid][0][0] + red[tid][1][0];
            aout_d[(size_t)r * DH + head] = red[tid][0][1] + red[tid][1][1];
        }
    }
}

template<int OUT_BF16, int DOTS, int DH>
__global__ __launch_bounds__(256) void gemm_mfma(
    const u16* __restrict__ A1, int lda1, int K1,
    const u16* __restrict__ A2, int lda2, int K2,
    const u16* __restrict__ Bw,
    void* __restrict__ Cout, int ldc,
    const float* __restrict__ bias,
    const float* __restrict__ dvs, const float* __restrict__ dvd,
    float* __restrict__ aout_s, float* __restrict__ aout_d)
{
    __shared__ u16 Asm[128 * 32];
    __shared__ u16 Bsm[128 * 32];
    gemm_body<OUT_BF16, DOTS, DH>(Asm, Bsm, A1, lda1, K1, A2, lda2, K2, Bw, Cout, ldc, bias,
                                  blockIdx.y * 128, blockIdx.x * 128, dvs, dvd, aout_s, aout_d);
}

// fused Q|K|V: blockIdx.x selects which product
__global__ __launch_bounds__(256) void gemm_qkv(
    const u16* __restrict__ xb,
    const u16* __restrict__ wqT, const u16* __restrict__ wkT, const u16* __restrict__ wvT,
    u16* __restrict__ qb, u16* __restrict__ kb, u16* __restrict__ vb)
{
    __shared__ u16 Asm[128 * 32];
    __shared__ u16 Bsm[128 * 32];
    const u16* A; const u16* B; int K; u16* C;
    if (blockIdx.x == 0)      { A = xb;       B = wqT; K = 128; C = qb; }
    else if (blockIdx.x == 1) { A = xb + 128; B = wkT; K = 768; C = kb; }
    else                      { A = xb + 128; B = wvT; K = 768; C = vb; }
    gemm_body<1, 0, 1>(Asm, Bsm, A, 896, K, (const u16*)nullptr, 0, 0, B, C, 128, nullptr,
                       blockIdx.y * 128, 0, nullptr, nullptr, nullptr, nullptr);
}

// ---------------- node cross-attention (bf16): V *= sigmoid(dot(Q,K)) ----------------
__global__ __launch_bounds__(128) void node_attn_b(const u16* __restrict__ Q,
                                                   const u16* __restrict__ K,
                                                   u16* __restrict__ V)
{
    int nd = blockIdx.x;
    int t = threadIdx.x;
    size_t base = (size_t)nd * HIDD;
    float p = bf2f(Q[base + t]) * bf2f(K[base + t]);
    #pragma unroll
    for (int off = 32; off; off >>= 1) p += __shfl_down(p, off);
    __shared__ float sm[2];
    if ((t & 63) == 0) sm[t >> 6] = p;
    __syncthreads();
    float s = sm[0] + sm[1];
    float sig = 1.f / (1.f + expf(-s));
    V[base + t] = f2bf(bf2f(V[base + t]) * sig);
}

// ---------------- fused softmax + gather aggregation (barrier-free, 8-deep MLP) ----------------
#define GATHER1(IDX, SS, AA) { \
    int SS = esrc[IDX]; \
    float AA = exf[(size_t)(IDX) * 4 + h]; \
    u32 p_ = *(const u32*)(h1b + (size_t)SS * H1D + c0); \
    den += AA; \
    n0 = fmaf(bf2f((u16)p_), AA, n0); \
    n1 = fmaf(bf2f((u16)(p_ >> 16)), AA, n1); }

__global__ __launch_bounds__(256) void agg1_f(const int* __restrict__ rowptr, const int* __restrict__ esrc,
    const float* __restrict__ exf,
    const u16* __restrict__ h1b, const float* __restrict__ bias, u16* __restrict__ o1b)
{
    int d = blockIdx.x;
    int t = threadIdx.x;
    int c0 = t * 2;
    int h = t >> 6;
    int beg = rowptr[d], end = rowptr[d + 1];
    float n0 = 0.f, n1 = 0.f, den = 0.f;
    int i = beg;
    for (; i + 7 < end; i += 8) {
        int s0 = esrc[i], s1 = esrc[i+1], s2 = esrc[i+2], s3 = esrc[i+3];
        int s4 = esrc[i+4], s5 = esrc[i+5], s6 = esrc[i+6], s7 = esrc[i+7];
        float a0 = exf[(size_t)i*4+h],     a1 = exf[(size_t)(i+1)*4+h];
        float a2 = exf[(size_t)(i+2)*4+h], a3 = exf[(size_t)(i+3)*4+h];
        float a4 = exf[(size_t)(i+4)*4+h], a5 = exf[(size_t)(i+5)*4+h];
        float a6 = exf[(size_t)(i+6)*4+h], a7 = exf[(size_t)(i+7)*4+h];
        u32 p0 = *(const u32*)(h1b + (size_t)s0 * H1D + c0);
        u32 p1 = *(const u32*)(h1b + (size_t)s1 * H1D + c0);
        u32 p2 = *(const u32*)(h1b + (size_t)s2 * H1D + c0);
        u32 p3 = *(const u32*)(h1b + (size_t)s3 * H1D + c0);
        u32 p4 = *(const u32*)(h1b + (size_t)s4 * H1D + c0);
        u32 p5 = *(const u32*)(h1b + (size_t)s5 * H1D + c0);
        u32 p6 = *(const u32*)(h1b + (size_t)s6 * H1D + c0);
        u32 p7 = *(const u32*)(h1b + (size_t)s7 * H1D + c0);
        den += ((a0 + a1) + (a2 + a3)) + ((a4 + a5) + (a6 + a7));
        n0 = fmaf(bf2f((u16)p0), a0, n0); n1 = fmaf(bf2f((u16)(p0 >> 16)), a0, n1);
        n0 = fmaf(bf2f((u16)p1), a1, n0); n1 = fmaf(bf2f((u16)(p1 >> 16)), a1, n1);
        n0 = fmaf(bf2f((u16)p2), a2, n0); n1 = fmaf(bf2f((u16)(p2 >> 16)), a2, n1);
        n0 = fmaf(bf2f((u16)p3), a3, n0); n1 = fmaf(bf2f((u16)(p3 >> 16)), a3, n1);
        n0 = fmaf(bf2f((u16)p4), a4, n0); n1 = fmaf(bf2f((u16)(p4 >> 16)), a4, n1);
        n0 = fmaf(bf2f((u16)p5), a5, n0); n1 = fmaf(bf2f((u16)(p5 >> 16)), a5, n1);
        n0 = fmaf(bf2f((u16)p6), a6, n0); n1 = fmaf(bf2f((u16)(p6 >> 16)), a6, n1);
        n0 = fmaf(bf2f((u16)p7), a7, n0); n1 = fmaf(bf2f((u16)(p7 >> 16)), a7, n1);
    }
    for (; i < end; ++i) GATHER1(i, sA, aA)
    float invd = 1.f / (den + 1e-16f);
    float a0o = n0 * invd + bias[c0];
    float a1o = n1 * invd + bias[c0 + 1];
    u32 o = (u32)f2bf(a0o) | ((u32)f2bf(a1o) << 16);
    *(u32*)(o1b + (size_t)d * H1D + c0) = o;
}

// layer 2: wave per dst (4/block); block 0 additionally zeroes msum/vsum for norm2.
__global__ __launch_bounds__(256) void agg2_f(const int* __restrict__ rowptr, const int* __restrict__ esrc,
    const float* __restrict__ exf,
    const u16* __restrict__ h2b, const float* __restrict__ bias, float* __restrict__ o2,
    float* __restrict__ msum)
{
    if (blockIdx.x == 0) {
        msum[threadIdx.x] = 0.f;
        msum[threadIdx.x + 256] = 0.f;
        msum[threadIdx.x + 512] = 0.f;
        msum[threadIdx.x + 768] = 0.f;
    }
    int w = threadIdx.x >> 6, l = threadIdx.x & 63;
    int d = blockIdx.x * 4 + w;
    if (d >= NN) return;
    int c0 = l * 2;
    int beg = rowptr[d], end = rowptr[d + 1];
    float n0 = 0.f, n1 = 0.f, den = 0.f;
    int i = beg;
    for (; i + 7 < end; i += 8) {
        int s0 = esrc[i], s1 = esrc[i+1], s2 = esrc[i+2], s3 = esrc[i+3];
        int s4 = esrc[i+4], s5 = esrc[i+5], s6 = esrc[i+6], s7 = esrc[i+7];
        float a0 = exf[i],   a1 = exf[i+1], a2 = exf[i+2], a3 = exf[i+3];
        float a4 = exf[i+4], a5 = exf[i+5], a6 = exf[i+6], a7 = exf[i+7];
        u32 p0 = *(const u32*)(h2b + (size_t)s0 * HIDD + c0);
        u32 p1 = *(const u32*)(h2b + (size_t)s1 * HIDD + c0);
        u32 p2 = *(const u32*)(h2b + (size_t)s2 * HIDD + c0);
        u32 p3 = *(const u32*)(h2b + (size_t)s3 * HIDD + c0);
        u32 p4 = *(const u32*)(h2b + (size_t)s4 * HIDD + c0);
        u32 p5 = *(const u32*)(h2b + (size_t)s5 * HIDD + c0);
        u32 p6 = *(const u32*)(h2b + (size_t)s6 * HIDD + c0);
        u32 p7 = *(const u32*)(h2b + (size_t)s7 * HIDD + c0);
        den += ((a0 + a1) + (a2 + a3)) + ((a4 + a5) + (a6 + a7));
        n0 = fmaf(bf2f((u16)p0), a0, n0); n1 = fmaf(bf2f((u16)(p0 >> 16)), a0, n1);
        n0 = fmaf(bf2f((u16)p1), a1, n0); n1 = fmaf(bf2f((u16)(p1 >> 16)), a1, n1);
        n0 = fmaf(bf2f((u16)p2), a2, n0); n1 = fmaf(bf2f((u16)(p2 >> 16)), a2, n1);
        n0 = fmaf(bf2f((u16)p3), a3, n0); n1 = fmaf(bf2f((u16)(p3 >> 16)), a3, n1);
        n0 = fmaf(bf2f((u16)p4), a4, n0); n1 = fmaf(bf2f((u16)(p4 >> 16)), a4, n1);
        n0 = fmaf(bf2f((u16)p5), a5, n0); n1 = fmaf(bf2f((u16)(p5 >> 16)), a5, n1);
        n0 = fmaf(bf2f((u16)p6), a6, n0); n1 = fmaf(bf2f((u16)(p6 >> 16)), a6, n1);
        n0 = fmaf(bf2f((u16)p7), a7, n0); n1 = fmaf(bf2f((u16)(p7 >> 16)), a7, n1);
    }
    for (; i < end; ++i) {
        int sA = esrc[i];
        float aA = exf[i];
        u32 pA = *(const u32*)(h2b + (size_t)sA * HIDD + c0);
        den += aA;
        n0 = fmaf(bf2f((u16)pA), aA, n0);
        n1 = fmaf(bf2f((u16)(pA >> 16)), aA, n1);
    }
    float invd = 1.f / (den + 1e-16f);
    o2[(size_t)d * HIDD + c0]     = n0 * invd + bias[c0];
    o2[(size_t)d * HIDD + c0 + 1] = n1 * invd + bias[c0 + 1];
}

// ---------------- graph norm ----------------
__global__ void colstat_b(const u16* __restrict__ x, float* __restrict__ msum,
                          float* __restrict__ vsum, int n, int rpb)
{
    int C = blockDim.x;
    int c = threadIdx.x;
    int r0 = blockIdx.x * rpb;
    int r1 = min(n, r0 + rpb);
    float s = 0.f, s2 = 0.f;
    for (int r = r0; r < r1; ++r) {
        float v = bf2f(x[(size_t)r * C + c]);
        s += v;
        s2 += v * v;
    }
    atomicAdd(&msum[c], s);
    atomicAdd(&vsum[c], s2);
}

__global__ void apply_norm_elu_b(u16* __restrict__ x, const float* __restrict__ msum,
                                 const float* __restrict__ vsum, const float* __restrict__ ms,
                                 const float* __restrict__ w, const float* __restrict__ b,
                                 int n, int rpb)
{
    int C = blockDim.x;
    int c = threadIdx.x;
    const float invn = 1.f / (float)NN;
    float mean = msum[c] * invn;
    float sub = mean * ms[c];
    float var = vsum[c] * invn - 2.f * sub * mean + sub * sub;
    float inv = rsqrtf(var + 1e-5f);
    float wc = w[c] * inv, bc = b[c];
    int r0 = blockIdx.x * rpb;
    int r1 = min(n, r0 + rpb);
    for (int r = r0; r < r1; ++r) {
        float v = (bf2f(x[(size_t)r * C + c]) - sub) * wc + bc;
        v = v > 0.f ? v : expm1f(v);
        x[(size_t)r * C + c] = f2bf(v);
    }
}

__global__ void colstat(const float* __restrict__ x, float* __restrict__ msum,
                        float* __restrict__ vsum, int n, int rpb)
{
    int C = blockDim.x;
    int c = threadIdx.x;
    int r0 = blockIdx.x * rpb;
    int r1 = min(n, r0 + rpb);
    float s = 0.f, s2 = 0.f;
    for (int r = r0; r < r1; ++r) {
        float v = x[(size_t)r * C + c];
        s += v;
        s2 += v * v;
    }
    atomicAdd(&msum[c], s);
    atomicAdd(&vsum[c], s2);
}

// ---------------- fused norm2 + ELU + final projection ----------------
__global__ __launch_bounds__(128) void norm2_proj(const float* __restrict__ o2,
    const float* __restrict__ msum, const float* __restrict__ vsum,
    const float* __restrict__ ms, const float* __restrict__ w, const float* __restrict__ b,
    const float* __restrict__ Wn, const float* __restrict__ bn, float* __restrict__ out)
{
    int nd = blockIdx.x;
    int t = threadIdx.x;
    const float invn = 1.f / (float)NN;
    float mean = msum[t] * invn;
    float sub = mean * ms[t];
    float var = vsum[t] * invn - 2.f * sub * mean + sub * sub;
    float inv = rsqrtf(var + 1e-5f);
    float v = (o2[(size_t)nd * HIDD + t] - sub) * w[t] * inv + b[t];
    v = v > 0.f ? v : expm1f(v);
    float p0 = v * Wn[t * 2], p1 = v * Wn[t * 2 + 1];
    #pragma unroll
    for (int off = 32; off; off >>= 1) {
        p0 += __shfl_down(p0, off);
        p1 += __shfl_down(p1, off);
    }
    __shared__ float sm[4];
    if ((t & 63) == 0) { sm[t >> 6] = p0; sm[2 + (t >> 6)] = p1; }
    __syncthreads();
    if (t == 0) {
        out[nd * 2 + 0] = sm[0] + sm[1] + bn[0];
        out[nd * 2 + 1] = sm[2] + sm[3] + bn[1];
    }
}

// ---------------- host launch ----------------
extern "C" void kernel_launch(void* const* d_in, const int* in_sizes, int n_in,
                              void* d_out, int out_size, void* d_ws, size_t ws_size,
                              hipStream_t stream)
{
    const float* x   = (const float*)d_in[0];
    const int*   ei  = (const int*)d_in[1];
    const float* Wq  = (const float*)d_in[2];
    const float* Wk  = (const float*)d_in[3];
    const float* Wv  = (const float*)d_in[4];
    const float* Wo  = (const float*)d_in[5];
    const float* bo  = (const float*)d_in[6];
    const float* W1  = (const float*)d_in[7];
    const float* as1 = (const float*)d_in[8];
    const float* ad1 = (const float*)d_in[9];
    const float* b1  = (const float*)d_in[10];
    const float* g1w = (const float*)d_in[11];
    const float* g1b = (const float*)d_in[12];
    const float* g1m = (const float*)d_in[13];
    const float* W2  = (const float*)d_in[14];
    const float* as2 = (const float*)d_in[15];
    const float* ad2 = (const float*)d_in[16];
    const float* b2  = (const float*)d_in[17];
    const float* g2w = (const float*)d_in[18];
    const float* g2b = (const float*)d_in[19];
    const float* g2m = (const float*)d_in[20];
    const float* Wn  = (const float*)d_in[21];
    const float* bn  = (const float*)d_in[22];
    float* out = (float*)d_out;

    // ---- workspace layout ----
    u16* usw = (u16*)d_ws;
    size_t uo = 0;
    u16* xb  = usw + uo; uo += (size_t)MP * 896;
    u16* h1b = usw + uo; uo += (size_t)MP * 512;
    u16* qb  = usw + uo; uo += (size_t)MP * 128;
    u16* kb  = usw + uo; uo += (size_t)MP * 128;   // later h2b
    u16* vb  = usw + uo; uo += (size_t)MP * 128;
    u16* o1b = usw + uo; uo += (size_t)MP * 512;
    u16* wqT = usw + uo; uo += 128 * 128;
    u16* wkT = usw + uo; uo += 128 * 768;
    u16* wvT = usw + uo; uo += 128 * 768;
    u16* woT = usw + uo; uo += 128 * 256;
    u16* w1T = usw + uo; uo += 512 * 896;
    u16* w2T = usw + uo; uo += 128 * 512;
    float* fws = (float*)(usw + uo);
    size_t fo = 0;
    float* asrc = fws + fo; fo += (size_t)MP * NHEADS;   // epilogue writes pad rows too
    float* adst = fws + fo; fo += (size_t)MP * NHEADS;
    float* exf  = fws + fo; fo += (size_t)EEDG * NHEADS;
    float* msum = fws + fo; fo += 512;
    float* vsum = fws + fo; fo += 512;
    int* iws = (int*)(fws + fo);
    size_t io = 0;
    int* rowptr = iws + io; io += NN + 1;
    int* degcur = iws + io; io += 2 * NN;     // [deg | cur]
    int* esrc   = iws + io; io += EEDG;
    int* edst   = iws + io; io += EEDG;
    int* spart  = iws + io; io += 256;
    int* cur    = degcur + NN;
    float* o2  = (float*)xb;   // xb free after h1 GEMM
    u16* h0b = qb;             // reuse q after node_attn
    u16* h2b = kb;             // reuse k after node_attn

    const int EB = (EEDG + 255) / 256;
    // cast_weights linear work: 770048 weights + 100000 ints + 1024 floats
    const int CW_BLOCKS = (770048 + 2 * NN + 1024 + 255) / 256;

    // --- init: all weight casts + zero fills in one dispatch ---
    cast_weights<<<CW_BLOCKS, 256, 0, stream>>>(Wq, Wk, Wv, Wo, W1, W2,
                                                wqT, wkT, wvT, woT, w1T, w2T,
                                                degcur, msum);
    cast_pad_x<<<8192, 256, 0, stream>>>((const float4*)x, xb);

    // --- CSR build ---
    count_deg<<<EB, 256, 0, stream>>>(ei, degcur);
    scan_bsum<<<SCAN_NB, 256, 0, stream>>>(degcur, spart);
    scan_part<<<1, 256, 0, stream>>>(spart);
    scan_write<<<SCAN_NB, 256, 0, stream>>>(degcur, spart, rowptr);
    fill_csr<<<EB, 256, 0, stream>>>(ei, rowptr, cur, esrc, edst);

    // --- cross attention: Q|K|V in one dispatch, then gate ---
    gemm_qkv<<<dim3(3, MT), 256, 0, stream>>>(xb, wqT, wkT, wvT, qb, kb, vb);
    node_attn_b<<<NN, 128, 0, stream>>>(qb, kb, vb);

    // --- h0 = [x_struct | attn] @ Wo + bo ---
    gemm_mfma<1, 0, 1><<<dim3(1, MT), 256, 0, stream>>>(xb, 896, 128, vb, 128, 128, woT, h0b, 128, bo,
                                                        nullptr, nullptr, nullptr, nullptr);

    // --- h1 = [h0 | x_sem] @ W1, att-dots fused in epilogue (col tile == head) ---
    gemm_mfma<1, 1, 4><<<dim3(4, MT), 256, 0, stream>>>(h0b, 128, 128, xb + 128, 896, 768, w1T, h1b, 512,
                                                        nullptr, as1, ad1, asrc, adst);

    // --- GAT layer 1: CSR-ordered edge exp -> barrier-free gather ---
    edge_exp<NHEADS><<<EB, 256, 0, stream>>>(esrc, edst, asrc, adst, exf);
    agg1_f<<<NN, 256, 0, stream>>>(rowptr, esrc, exf, h1b, b1, o1b);

    // --- graph norm 1 + ELU (bf16 in place) ---
    colstat_b<<<(NN + 127) / 128, H1D, 0, stream>>>(o1b, msum, vsum, NN, 128);
    apply_norm_elu_b<<<(NN + 127) / 128, H1D, 0, stream>>>(o1b, msum, vsum, g1m, g1w, g1b, NN, 128);

    // --- GAT layer 2: W2 GEMM with fused att-dots ---
    gemm_mfma<1, 1, 1><<<dim3(1, MT), 256, 0, stream>>>(o1b, 512, 512, (const u16*)nullptr, 0, 0, w2T, h2b, 128,
                                                        nullptr, as2, ad2, asrc, adst);
    edge_exp<1><<<EB, 256, 0, stream>>>(esrc, edst, asrc, adst, exf);
    agg2_f<<<(NN + 3) / 4, 256, 0, stream>>>(rowptr, esrc, exf, h2b, b2, o2, msum);

    // --- graph norm 2 + ELU + projection (fused) ---
    colstat<<<(NN + 127) / 128, HIDD, 0, stream>>>(o2, msum, vsum, NN, 128);
    norm2_proj<<<NN, 128, 0, stream>>>(o2, msum, vsum, g2m, g2w, g2b, Wn, bn, out);
}

// Round 9
// 608.386 us; speedup vs baseline: 1.2052x; 1.0442x over previous
//
#include <hip/hip_runtime.h>
#include <math.h>

#define NN 50000
#define NE 500000
#define EEDG 550000          // NE + NN self loops
#define SDIM 128             // STRUCT
#define MDIM 768             // SEM
#define HIDD 128             // HID
#define NHEADS 4
#define INDIM 896            // STRUCT + SEM
#define H1D 512              // HEADS*HID
#define SCAN_NB 196          // ceil(NN/256)
#define MP 50048             // NN padded to 128*391
#define MT 391               // row tiles of 128

typedef unsigned short u16;
typedef unsigned int u32;
typedef __attribute__((ext_vector_type(8))) short short8;
typedef __attribute__((ext_vector_type(4))) float f32x4;

// ---------------- bf16 helpers ----------------
__device__ __forceinline__ u16 f2bf(float f) {
    union { float f; u32 u; } v; v.f = f;
    u32 r = v.u + 0x7FFFu + ((v.u >> 16) & 1u);
    return (u16)(r >> 16);
}
__device__ __forceinline__ float bf2f(u16 h) {
    union { u32 u; float f; } v; v.u = ((u32)h) << 16;
    return v.f;
}

__device__ __forceinline__ void gl_lds16(const u16* g, u16* l) {
    __builtin_amdgcn_global_load_lds(
        (const __attribute__((address_space(1))) void*)g,
        (__attribute__((address_space(3))) void*)l, 16, 0, 0);
}

// ---------------- utility ----------------
__device__ __forceinline__ void edge_sd(const int* __restrict__ ei, int e, int& s, int& d) {
    if (e < NE) { s = ei[e]; d = ei[NE + e]; }
    else        { s = e - NE; d = e - NE; }
}

// ---------------- fused init: all weight casts (transposed) + zero fills ----------------
__global__ __launch_bounds__(256) void cast_weights(
    const float* __restrict__ Wq, const float* __restrict__ Wk, const float* __restrict__ Wv,
    const float* __restrict__ Wo, const float* __restrict__ W1, const float* __restrict__ W2,
    u16* __restrict__ wqT, u16* __restrict__ wkT, u16* __restrict__ wvT,
    u16* __restrict__ woT, u16* __restrict__ w1T, u16* __restrict__ w2T,
    int* __restrict__ degcur, float* __restrict__ msum)
{
    const int SQ = 128 * 128, SK = 128 * 768, SV = 128 * 768,
              SO = 256 * 128, S1 = 896 * 512, S2 = 512 * 128;
    long i = (long)blockIdx.x * 256 + threadIdx.x;
    long w = i;
    if (w < SQ) { int n = (int)(w / 128), k = (int)(w % 128); wqT[w] = f2bf(Wq[(size_t)k * 128 + n]); return; }
    w -= SQ;
    if (w < SK) { int n = (int)(w / 768), k = (int)(w % 768); wkT[w] = f2bf(Wk[(size_t)k * 128 + n]); return; }
    w -= SK;
    if (w < SV) { int n = (int)(w / 768), k = (int)(w % 768); wvT[w] = f2bf(Wv[(size_t)k * 128 + n]); return; }
    w -= SV;
    if (w < SO) { int n = (int)(w / 256), k = (int)(w % 256); woT[w] = f2bf(Wo[(size_t)k * 128 + n]); return; }
    w -= SO;
    if (w < S1) { int n = (int)(w / 896), k = (int)(w % 896); w1T[w] = f2bf(W1[(size_t)k * 512 + n]); return; }
    w -= S1;
    if (w < S2) { int n = (int)(w / 512), k = (int)(w % 512); w2T[w] = f2bf(W2[(size_t)k * 128 + n]); return; }
    w -= S2;
    if (w < 2 * NN) { degcur[w] = 0; return; }
    w -= 2 * NN;
    if (w < 1024) msum[w] = 0.f;
}

// ---------------- x cast + pad ----------------
__global__ __launch_bounds__(256) void cast_pad_x(const float4* __restrict__ x4, u16* __restrict__ xb) {
    const long total = (long)MP * 224;
    long i = (long)blockIdx.x * blockDim.x + threadIdx.x;
    long stride = (long)gridDim.x * blockDim.x;
    for (; i < total; i += stride) {
        int row = (int)(i / 224);
        int c4 = (int)(i - (long)row * 224);
        float4 v = make_float4(0.f, 0.f, 0.f, 0.f);
        if (row < NN) v = x4[(size_t)row * 224 + c4];
        short4 o;
        o.x = (short)f2bf(v.x); o.y = (short)f2bf(v.y);
        o.z = (short)f2bf(v.z); o.w = (short)f2bf(v.w);
        *(short4*)(xb + (size_t)row * 896 + c4 * 4) = o;
    }
}

// ---------------- CSR build ----------------
__global__ __launch_bounds__(256) void count_deg(const int* __restrict__ ei, int* __restrict__ deg) {
    int e = blockIdx.x * 256 + threadIdx.x;
    if (e >= EEDG) return;
    int d = e < NE ? ei[NE + e] : e - NE;
    atomicAdd(&deg[d], 1);
}

__global__ __launch_bounds__(256) void scan_bsum(const int* __restrict__ deg, int* __restrict__ part) {
    __shared__ int s[256];
    int t = threadIdx.x;
    int idx = blockIdx.x * 256 + t;
    s[t] = idx < NN ? deg[idx] : 0;
    __syncthreads();
    for (int off = 128; off; off >>= 1) {
        if (t < off) s[t] += s[t + off];
        __syncthreads();
    }
    if (t == 0) part[blockIdx.x] = s[0];
}

__global__ __launch_bounds__(256) void scan_part(int* __restrict__ part) {
    __shared__ int s[256];
    int t = threadIdx.x;
    int v = t < SCAN_NB ? part[t] : 0;
    s[t] = v;
    __syncthreads();
    for (int off = 1; off < 256; off <<= 1) {
        int x = t >= off ? s[t - off] : 0;
        __syncthreads();
        s[t] += x;
        __syncthreads();
    }
    if (t < SCAN_NB) part[t] = s[t] - v;   // exclusive
}

__global__ __launch_bounds__(256) void scan_write(const int* __restrict__ deg, const int* __restrict__ part,
                                                  int* __restrict__ rowptr) {
    __shared__ int s[256];
    int t = threadIdx.x;
    int idx = blockIdx.x * 256 + t;
    int v = idx < NN ? deg[idx] : 0;
    s[t] = v;
    __syncthreads();
    for (int off = 1; off < 256; off <<= 1) {
        int x = t >= off ? s[t - off] : 0;
        __syncthreads();
        s[t] += x;
        __syncthreads();
    }
    if (idx < NN) rowptr[idx] = part[blockIdx.x] + s[t] - v;
    if (idx == NN - 1) rowptr[NN] = EEDG;
}

__global__ __launch_bounds__(256) void fill_csr(const int* __restrict__ ei, const int* __restrict__ rowptr,
                                                int* __restrict__ cur, int* __restrict__ esrc,
                                                int* __restrict__ edst) {
    int e = blockIdx.x * 256 + threadIdx.x;
    if (e >= EEDG) return;
    int s, d;
    edge_sd(ei, e, s, d);
    int p = rowptr[d] + atomicAdd(&cur[d], 1);
    esrc[p] = s;
    edst[p] = d;
}

// ---------------- CSR-ordered per-edge softmax numerators ----------------
template<int H>
__global__ __launch_bounds__(256) void edge_exp(const int* __restrict__ esrc, const int* __restrict__ edst,
    const float* __restrict__ asrc, const float* __restrict__ adst, float* __restrict__ exf)
{
    int i = blockIdx.x * 256 + threadIdx.x;
    if (i >= EEDG) return;
    int s = esrc[i], d = edst[i];
    if (H == 4) {
        float4 as = *(const float4*)(asrc + s * 4);
        float4 ad = *(const float4*)(adst + d * 4);
        float4 o;
        float a;
        a = as.x + ad.x; a = a >= 0.f ? a : 0.2f * a; o.x = expf(a);
        a = as.y + ad.y; a = a >= 0.f ? a : 0.2f * a; o.y = expf(a);
        a = as.z + ad.z; a = a >= 0.f ? a : 0.2f * a; o.z = expf(a);
        a = as.w + ad.w; a = a >= 0.f ? a : 0.2f * a; o.w = expf(a);
        *(float4*)(exf + (size_t)i * 4) = o;
    } else {
        float a = asrc[s] + adst[d];
        a = a >= 0.f ? a : 0.2f * a;
        exf[i] = expf(a);
    }
}

// ---------------- MFMA bf16 GEMM body (optional fused att-dot epilogue) ----------------
template<int OUT_BF16, int DOTS, int DH>
__device__ __forceinline__ void gemm_body(
    u16* __restrict__ Asm, u16* __restrict__ Bsm,
    const u16* __restrict__ A1, int lda1, int K1,
    const u16* __restrict__ A2, int lda2, int K2,
    const u16* __restrict__ Bw,
    void* __restrict__ Cout, int ldc,
    const float* __restrict__ bias, int row0, int col0,
    const float* __restrict__ dvs, const float* __restrict__ dvd,
    float* __restrict__ aout_s, float* __restrict__ aout_d)
{
    const int tid = threadIdx.x;
    const int wave = tid >> 6, lane = tid & 63;
    const int wr = wave >> 1, wc = wave & 1;
    const int K = K1 + K2;
    const int srow = tid >> 2;
    const int skp = (tid & 3) * 8;
    const int l15 = lane & 15, l4 = lane >> 4;

    f32x4 acc[4][4];
    #pragma unroll
    for (int i = 0; i < 4; ++i)
        #pragma unroll
        for (int j = 0; j < 4; ++j)
            acc[i][j] = (f32x4){0.f, 0.f, 0.f, 0.f};

    for (int k0 = 0; k0 < K; k0 += 32) {
        const u16* Ab; int la; int kk;
        if (k0 < K1) { Ab = A1; la = lda1; kk = k0; }
        else         { Ab = A2; la = lda2; kk = k0 - K1; }
        gl_lds16(Ab + (size_t)(row0 + srow) * la + kk + skp,      Asm + srow * 32 + skp);
        gl_lds16(Ab + (size_t)(row0 + srow + 64) * la + kk + skp, Asm + (srow + 64) * 32 + skp);
        gl_lds16(Bw + (size_t)(col0 + srow) * K + k0 + skp,       Bsm + srow * 32 + skp);
        gl_lds16(Bw + (size_t)(col0 + srow + 64) * K + k0 + skp,  Bsm + (srow + 64) * 32 + skp);
        __syncthreads();
        short8 af[4], bfr[4];
        #pragma unroll
        for (int m = 0; m < 4; ++m)
            af[m] = *(const short8*)(Asm + (wr * 64 + m * 16 + l15) * 32 + l4 * 8);
        #pragma unroll
        for (int n = 0; n < 4; ++n)
            bfr[n] = *(const short8*)(Bsm + (wc * 64 + n * 16 + l15) * 32 + l4 * 8);
        #pragma unroll
        for (int m = 0; m < 4; ++m)
            #pragma unroll
            for (int n = 0; n < 4; ++n)
                acc[m][n] = __builtin_amdgcn_mfma_f32_16x16x32_bf16(af[m], bfr[n], acc[m][n], 0, 0, 0);
        __syncthreads();
    }
    #pragma unroll
    for (int m = 0; m < 4; ++m) {
        int r = row0 + wr * 64 + m * 16 + l4 * 4;
        #pragma unroll
        for (int n = 0; n < 4; ++n) {
            int c = col0 + wc * 64 + n * 16 + l15;
            float bv = bias ? bias[c] : 0.f;
            #pragma unroll
            for (int q = 0; q < 4; ++q) {
                float v = acc[m][n][q] + bv;
                if (OUT_BF16) ((u16*)Cout)[(size_t)(r + q) * ldc + c] = f2bf(v);
                else          ((float*)Cout)[(size_t)(r + q) * ldc + c] = v;
            }
        }
    }
    if (DOTS) {
        const int head = (DH == 1) ? 0 : (col0 >> 7);
        const float* svp = dvs + head * 128;
        const float* dvp = dvd + head * 128;
        float sv[4], dv[4];
        #pragma unroll
        for (int n = 0; n < 4; ++n) {
            int cc = wc * 64 + n * 16 + l15;
            sv[n] = svp[cc];
            dv[n] = dvp[cc];
        }
        __shared__ float red[128][2][2];
        #pragma unroll
        for (int m = 0; m < 4; ++m) {
            #pragma unroll
            for (int q = 0; q < 4; ++q) {
                float ps = 0.f, pd = 0.f;
                #pragma unroll
                for (int n = 0; n < 4; ++n) {
                    ps = fmaf(acc[m][n][q], sv[n], ps);
                    pd = fmaf(acc[m][n][q], dv[n], pd);
                }
                #pragma unroll
                for (int off = 1; off < 16; off <<= 1) {
                    ps += __shfl_xor(ps, off);
                    pd += __shfl_xor(pd, off);
                }
                if (l15 == 0) {
                    int lr = wr * 64 + m * 16 + l4 * 4 + q;
                    red[lr][wc][0] = ps;
                    red[lr][wc][1] = pd;
                }
            }
        }
        __syncthreads();
        if (tid < 128) {
            int r = row0 + tid;
            aout_s[(size_t)r * DH + head] = red[tid][0][0] + red[tid][1][0];
            aout_d[(size_t)r * DH + head] = red[tid][0][1] + red[tid][1][1];
        }
    }
}

template<int OUT_BF16, int DOTS, int DH>
__global__ __launch_bounds__(256) void gemm_mfma(
    const u16* __restrict__ A1, int lda1, int K1,
    const u16* __restrict__ A2, int lda2, int K2,
    const u16* __restrict__ Bw,
    void* __restrict__ Cout, int ldc,
    const float* __restrict__ bias,
    const float* __restrict__ dvs, const float* __restrict__ dvd,
    float* __restrict__ aout_s, float* __restrict__ aout_d)
{
    __shared__ u16 Asm[128 * 32];
    __shared__ u16 Bsm[128 * 32];
    gemm_body<OUT_BF16, DOTS, DH>(Asm, Bsm, A1, lda1, K1, A2, lda2, K2, Bw, Cout, ldc, bias,
                                  blockIdx.y * 128, blockIdx.x * 128, dvs, dvd, aout_s, aout_d);
}

// W1 GEMM: 1D grid with bijective XCD-chunked swizzle; col tile fastest within
// each XCD's contiguous logical span -> A row-panel reused 4x inside one L2.
__global__ __launch_bounds__(256) void gemm_w1(
    const u16* __restrict__ A1, const u16* __restrict__ A2,
    const u16* __restrict__ Bw, u16* __restrict__ Cout)
{
    __shared__ u16 Asm[128 * 32];
    __shared__ u16 Bsm[128 * 32];
    const int nwg = 4 * MT;            // 1564
    const int q = nwg / 8, r = nwg % 8;
    int orig = blockIdx.x;
    int xcd = orig & 7;
    int lg = (xcd < r ? xcd * (q + 1) : r * (q + 1) + (xcd - r) * q) + (orig >> 3);
    int col0 = (lg & 3) * 128;
    int row0 = (lg >> 2) * 128;
    gemm_body<1, 0, 1>(Asm, Bsm, A1, 128, 128, A2, 896, 768, Bw, Cout, 512, nullptr,
                       row0, col0, nullptr, nullptr, nullptr, nullptr);
}

// fused Q|K|V: blockIdx.x selects which product
__global__ __launch_bounds__(256) void gemm_qkv(
    const u16* __restrict__ xb,
    const u16* __restrict__ wqT, const u16* __restrict__ wkT, const u16* __restrict__ wvT,
    u16* __restrict__ qb, u16* __restrict__ kb, u16* __restrict__ vb)
{
    __shared__ u16 Asm[128 * 32];
    __shared__ u16 Bsm[128 * 32];
    const u16* A; const u16* B; int K; u16* C;
    if (blockIdx.x == 0)      { A = xb;       B = wqT; K = 128; C = qb; }
    else if (blockIdx.x == 1) { A = xb + 128; B = wkT; K = 768; C = kb; }
    else                      { A = xb + 128; B = wvT; K = 768; C = vb; }
    gemm_body<1, 0, 1>(Asm, Bsm, A, 896, K, (const u16*)nullptr, 0, 0, B, C, 128, nullptr,
                       blockIdx.y * 128, 0, nullptr, nullptr, nullptr, nullptr);
}

// ---------------- node cross-attention (bf16): V *= sigmoid(dot(Q,K)) ----------------
__global__ __launch_bounds__(128) void node_attn_b(const u16* __restrict__ Q,
                                                   const u16* __restrict__ K,
                                                   u16* __restrict__ V)
{
    int nd = blockIdx.x;
    int t = threadIdx.x;
    size_t base = (size_t)nd * HIDD;
    float p = bf2f(Q[base + t]) * bf2f(K[base + t]);
    #pragma unroll
    for (int off = 32; off; off >>= 1) p += __shfl_down(p, off);
    __shared__ float sm[2];
    if ((t & 63) == 0) sm[t >> 6] = p;
    __syncthreads();
    float s = sm[0] + sm[1];
    float sig = 1.f / (1.f + expf(-s));
    V[base + t] = f2bf(bf2f(V[base + t]) * sig);
}

// ---------------- GAT layer-1 attention dots (from h1) ----------------
__global__ __launch_bounds__(256) void att_dots1_b(const u16* __restrict__ h1,
    const float* __restrict__ asv, const float* __restrict__ adv,
    float* __restrict__ a_src, float* __restrict__ a_dst)
{
    int nd = blockIdx.x;
    int t = threadIdx.x;
    int w = t >> 6, l = t & 63;
    const u16* hr = h1 + (size_t)nd * H1D + w * HIDD;
    const float* sv = asv + w * HIDD;
    const float* dv = adv + w * HIDD;
    float h0v = bf2f(hr[l]), h1v = bf2f(hr[l + 64]);
    float ps = h0v * sv[l] + h1v * sv[l + 64];
    float pd = h0v * dv[l] + h1v * dv[l + 64];
    #pragma unroll
    for (int off = 32; off; off >>= 1) {
        ps += __shfl_down(ps, off);
        pd += __shfl_down(pd, off);
    }
    if (l == 0) { a_src[nd * NHEADS + w] = ps; a_dst[nd * NHEADS + w] = pd; }
}

// ---------------- fused softmax + gather aggregation (barrier-free, 8-deep MLP) ----------------
// layer 1: 128 threads x 4 cols (uint2 loads -> 512B/wave bursts), 8-edge unroll.
#define ACC4(P, AA) { \
    n0 = fmaf(bf2f((u16)(P).x), AA, n0); \
    n1 = fmaf(bf2f((u16)((P).x >> 16)), AA, n1); \
    n2 = fmaf(bf2f((u16)(P).y), AA, n2); \
    n3 = fmaf(bf2f((u16)((P).y >> 16)), AA, n3); }

__global__ __launch_bounds__(128) void agg1_f(const int* __restrict__ rowptr, const int* __restrict__ esrc,
    const float* __restrict__ exf,
    const u16* __restrict__ h1b, const float* __restrict__ bias, u16* __restrict__ o1b)
{
    int d = blockIdx.x;
    int t = threadIdx.x;
    int c0 = t * 4;
    int h = t >> 5;
    int beg = rowptr[d], end = rowptr[d + 1];
    float n0 = 0.f, n1 = 0.f, n2 = 0.f, n3 = 0.f, den = 0.f;
    int i = beg;
    for (; i + 7 < end; i += 8) {
        int s0 = esrc[i], s1 = esrc[i+1], s2 = esrc[i+2], s3 = esrc[i+3];
        int s4 = esrc[i+4], s5 = esrc[i+5], s6 = esrc[i+6], s7 = esrc[i+7];
        float a0 = exf[(size_t)i*4+h],     a1 = exf[(size_t)(i+1)*4+h];
        float a2 = exf[(size_t)(i+2)*4+h], a3 = exf[(size_t)(i+3)*4+h];
        float a4 = exf[(size_t)(i+4)*4+h], a5 = exf[(size_t)(i+5)*4+h];
        float a6 = exf[(size_t)(i+6)*4+h], a7 = exf[(size_t)(i+7)*4+h];
        uint2 p0 = *(const uint2*)(h1b + (size_t)s0 * H1D + c0);
        uint2 p1 = *(const uint2*)(h1b + (size_t)s1 * H1D + c0);
        uint2 p2 = *(const uint2*)(h1b + (size_t)s2 * H1D + c0);
        uint2 p3 = *(const uint2*)(h1b + (size_t)s3 * H1D + c0);
        uint2 p4 = *(const uint2*)(h1b + (size_t)s4 * H1D + c0);
        uint2 p5 = *(const uint2*)(h1b + (size_t)s5 * H1D + c0);
        uint2 p6 = *(const uint2*)(h1b + (size_t)s6 * H1D + c0);
        uint2 p7 = *(const uint2*)(h1b + (size_t)s7 * H1D + c0);
        den += ((a0 + a1) + (a2 + a3)) + ((a4 + a5) + (a6 + a7));
        ACC4(p0, a0) ACC4(p1, a1) ACC4(p2, a2) ACC4(p3, a3)
        ACC4(p4, a4) ACC4(p5, a5) ACC4(p6, a6) ACC4(p7, a7)
    }
    for (; i < end; ++i) {
        int sA = esrc[i];
        float aA = exf[(size_t)i * 4 + h];
        uint2 pA = *(const uint2*)(h1b + (size_t)sA * H1D + c0);
        den += aA;
        ACC4(pA, aA)
    }
    float invd = 1.f / (den + 1e-16f);
    float4 bv = *(const float4*)(bias + c0);
    u32 o0 = (u32)f2bf(n0 * invd + bv.x) | ((u32)f2bf(n1 * invd + bv.y) << 16);
    u32 o1 = (u32)f2bf(n2 * invd + bv.z) | ((u32)f2bf(n3 * invd + bv.w) << 16);
    *(uint2*)(o1b + (size_t)d * H1D + c0) = make_uint2(o0, o1);
}

// layer 2: wave per dst (4/block); block 0 additionally zeroes msum/vsum for norm2.
__global__ __launch_bounds__(256) void agg2_f(const int* __restrict__ rowptr, const int* __restrict__ esrc,
    const float* __restrict__ exf,
    const u16* __restrict__ h2b, const float* __restrict__ bias, float* __restrict__ o2,
    float* __restrict__ msum)
{
    if (blockIdx.x == 0) {
        msum[threadIdx.x] = 0.f;
        msum[threadIdx.x + 256] = 0.f;
        msum[threadIdx.x + 512] = 0.f;
        msum[threadIdx.x + 768] = 0.f;
    }
    int w = threadIdx.x >> 6, l = threadIdx.x & 63;
    int d = blockIdx.x * 4 + w;
    if (d >= NN) return;
    int c0 = l * 2;
    int beg = rowptr[d], end = rowptr[d + 1];
    float n0 = 0.f, n1 = 0.f, den = 0.f;
    int i = beg;
    for (; i + 7 < end; i += 8) {
        int s0 = esrc[i], s1 = esrc[i+1], s2 = esrc[i+2], s3 = esrc[i+3];
        int s4 = esrc[i+4], s5 = esrc[i+5], s6 = esrc[i+6], s7 = esrc[i+7];
        float a0 = exf[i],   a1 = exf[i+1], a2 = exf[i+2], a3 = exf[i+3];
        float a4 = exf[i+4], a5 = exf[i+5], a6 = exf[i+6], a7 = exf[i+7];
        u32 p0 = *(const u32*)(h2b + (size_t)s0 * HIDD + c0);
        u32 p1 = *(const u32*)(h2b + (size_t)s1 * HIDD + c0);
        u32 p2 = *(const u32*)(h2b + (size_t)s2 * HIDD + c0);
        u32 p3 = *(const u32*)(h2b + (size_t)s3 * HIDD + c0);
        u32 p4 = *(const u32*)(h2b + (size_t)s4 * HIDD + c0);
        u32 p5 = *(const u32*)(h2b + (size_t)s5 * HIDD + c0);
        u32 p6 = *(const u32*)(h2b + (size_t)s6 * HIDD + c0);
        u32 p7 = *(const u32*)(h2b + (size_t)s7 * HIDD + c0);
        den += ((a0 + a1) + (a2 + a3)) + ((a4 + a5) + (a6 + a7));
        n0 = fmaf(bf2f((u16)p0), a0, n0); n1 = fmaf(bf2f((u16)(p0 >> 16)), a0, n1);
        n0 = fmaf(bf2f((u16)p1), a1, n0); n1 = fmaf(bf2f((u16)(p1 >> 16)), a1, n1);
        n0 = fmaf(bf2f((u16)p2), a2, n0); n1 = fmaf(bf2f((u16)(p2 >> 16)), a2, n1);
        n0 = fmaf(bf2f((u16)p3), a3, n0); n1 = fmaf(bf2f((u16)(p3 >> 16)), a3, n1);
        n0 = fmaf(bf2f((u16)p4), a4, n0); n1 = fmaf(bf2f((u16)(p4 >> 16)), a4, n1);
        n0 = fmaf(bf2f((u16)p5), a5, n0); n1 = fmaf(bf2f((u16)(p5 >> 16)), a5, n1);
        n0 = fmaf(bf2f((u16)p6), a6, n0); n1 = fmaf(bf2f((u16)(p6 >> 16)), a6, n1);
        n0 = fmaf(bf2f((u16)p7), a7, n0); n1 = fmaf(bf2f((u16)(p7 >> 16)), a7, n1);
    }
    for (; i < end; ++i) {
        int sA = esrc[i];
        float aA = exf[i];
        u32 pA = *(const u32*)(h2b + (size_t)sA * HIDD + c0);
        den += aA;
        n0 = fmaf(bf2f((u16)pA), aA, n0);
        n1 = fmaf(bf2f((u16)(pA >> 16)), aA, n1);
    }
    float invd = 1.f / (den + 1e-16f);
    o2[(size_t)d * HIDD + c0]     = n0 * invd + bias[c0];
    o2[(size_t)d * HIDD + c0 + 1] = n1 * invd + bias[c0 + 1];
}

// ---------------- graph norm ----------------
__global__ void colstat_b(const u16* __restrict__ x, float* __restrict__ msum,
                          float* __restrict__ vsum, int n, int rpb)
{
    int C = blockDim.x;
    int c = threadIdx.x;
    int r0 = blockIdx.x * rpb;
    int r1 = min(n, r0 + rpb);
    float s = 0.f, s2 = 0.f;
    for (int r = r0; r < r1; ++r) {
        float v = bf2f(x[(size_t)r * C + c]);
        s += v;
        s2 += v * v;
    }
    atomicAdd(&msum[c], s);
    atomicAdd(&vsum[c], s2);
}

__global__ void apply_norm_elu_b(u16* __restrict__ x, const float* __restrict__ msum,
                                 const float* __restrict__ vsum, const float* __restrict__ ms,
                                 const float* __restrict__ w, const float* __restrict__ b,
                                 int n, int rpb)
{
    int C = blockDim.x;
    int c = threadIdx.x;
    const float invn = 1.f / (float)NN;
    float mean = msum[c] * invn;
    float sub = mean * ms[c];
    float var = vsum[c] * invn - 2.f * sub * mean + sub * sub;
    float inv = rsqrtf(var + 1e-5f);
    float wc = w[c] * inv, bc = b[c];
    int r0 = blockIdx.x * rpb;
    int r1 = min(n, r0 + rpb);
    for (int r = r0; r < r1; ++r) {
        float v = (bf2f(x[(size_t)r * C + c]) - sub) * wc + bc;
        v = v > 0.f ? v : expm1f(v);
        x[(size_t)r * C + c] = f2bf(v);
    }
}

__global__ void colstat(const float* __restrict__ x, float* __restrict__ msum,
                        float* __restrict__ vsum, int n, int rpb)
{
    int C = blockDim.x;
    int c = threadIdx.x;
    int r0 = blockIdx.x * rpb;
    int r1 = min(n, r0 + rpb);
    float s = 0.f, s2 = 0.f;
    for (int r = r0; r < r1; ++r) {
        float v = x[(size_t)r * C + c];
        s += v;
        s2 += v * v;
    }
    atomicAdd(&msum[c], s);
    atomicAdd(&vsum[c], s2);
}

// ---------------- fused norm2 + ELU + final projection ----------------
__global__ __launch_bounds__(128) void norm2_proj(const float* __restrict__ o2,
    const float* __restrict__ msum, const float* __restrict__ vsum,
    const float* __restrict__ ms, const float* __restrict__ w, const float* __restrict__ b,
    const float* __restrict__ Wn, const float* __restrict__ bn, float* __restrict__ out)
{
    int nd = blockIdx.x;
    int t = threadIdx.x;
    const float invn = 1.f / (float)NN;
    float mean = msum[t] * invn;
    float sub = mean * ms[t];
    float var = vsum[t] * invn - 2.f * sub * mean + sub * sub;
    float inv = rsqrtf(var + 1e-5f);
    float v = (o2[(size_t)nd * HIDD + t] - sub) * w[t] * inv + b[t];
    v = v > 0.f ? v : expm1f(v);
    float p0 = v * Wn[t * 2], p1 = v * Wn[t * 2 + 1];
    #pragma unroll
    for (int off = 32; off; off >>= 1) {
        p0 += __shfl_down(p0, off);
        p1 += __shfl_down(p1, off);
    }
    __shared__ float sm[4];
    if ((t & 63) == 0) { sm[t >> 6] = p0; sm[2 + (t >> 6)] = p1; }
    __syncthreads();
    if (t == 0) {
        out[nd * 2 + 0] = sm[0] + sm[1] + bn[0];
        out[nd * 2 + 1] = sm[2] + sm[3] + bn[1];
    }
}

// ---------------- host launch ----------------
extern "C" void kernel_launch(void* const* d_in, const int* in_sizes, int n_in,
                              void* d_out, int out_size, void* d_ws, size_t ws_size,
                              hipStream_t stream)
{
    const float* x   = (const float*)d_in[0];
    const int*   ei  = (const int*)d_in[1];
    const float* Wq  = (const float*)d_in[2];
    const float* Wk  = (const float*)d_in[3];
    const float* Wv  = (const float*)d_in[4];
    const float* Wo  = (const float*)d_in[5];
    const float* bo  = (const float*)d_in[6];
    const float* W1  = (const float*)d_in[7];
    const float* as1 = (const float*)d_in[8];
    const float* ad1 = (const float*)d_in[9];
    const float* b1  = (const float*)d_in[10];
    const float* g1w = (const float*)d_in[11];
    const float* g1b = (const float*)d_in[12];
    const float* g1m = (const float*)d_in[13];
    const float* W2  = (const float*)d_in[14];
    const float* as2 = (const float*)d_in[15];
    const float* ad2 = (const float*)d_in[16];
    const float* b2  = (const float*)d_in[17];
    const float* g2w = (const float*)d_in[18];
    const float* g2b = (const float*)d_in[19];
    const float* g2m = (const float*)d_in[20];
    const float* Wn  = (const float*)d_in[21];
    const float* bn  = (const float*)d_in[22];
    float* out = (float*)d_out;

    // ---- workspace layout ----
    u16* usw = (u16*)d_ws;
    size_t uo = 0;
    u16* xb  = usw + uo; uo += (size_t)MP * 896;
    u16* h1b = usw + uo; uo += (size_t)MP * 512;
    u16* qb  = usw + uo; uo += (size_t)MP * 128;
    u16* kb  = usw + uo; uo += (size_t)MP * 128;   // later h2b
    u16* vb  = usw + uo; uo += (size_t)MP * 128;
    u16* o1b = usw + uo; uo += (size_t)MP * 512;
    u16* wqT = usw + uo; uo += 128 * 128;
    u16* wkT = usw + uo; uo += 128 * 768;
    u16* wvT = usw + uo; uo += 128 * 768;
    u16* woT = usw + uo; uo += 128 * 256;
    u16* w1T = usw + uo; uo += 512 * 896;
    u16* w2T = usw + uo; uo += 128 * 512;
    float* fws = (float*)(usw + uo);
    size_t fo = 0;
    float* asrc = fws + fo; fo += (size_t)MP * NHEADS;
    float* adst = fws + fo; fo += (size_t)MP * NHEADS;
    float* exf  = fws + fo; fo += (size_t)EEDG * NHEADS;
    float* msum = fws + fo; fo += 512;
    float* vsum = fws + fo; fo += 512;
    int* iws = (int*)(fws + fo);
    size_t io = 0;
    int* rowptr = iws + io; io += NN + 1;
    int* degcur = iws + io; io += 2 * NN;     // [deg | cur]
    int* esrc   = iws + io; io += EEDG;
    int* edst   = iws + io; io += EEDG;
    int* spart  = iws + io; io += 256;
    int* cur    = degcur + NN;
    float* o2  = (float*)xb;   // xb free after h1 GEMM
    u16* h0b = qb;             // reuse q after node_attn
    u16* h2b = kb;             // reuse k after node_attn

    const int EB = (EEDG + 255) / 256;
    const int CW_BLOCKS = (770048 + 2 * NN + 1024 + 255) / 256;

    // --- init: all weight casts + zero fills in one dispatch ---
    cast_weights<<<CW_BLOCKS, 256, 0, stream>>>(Wq, Wk, Wv, Wo, W1, W2,
                                                wqT, wkT, wvT, woT, w1T, w2T,
                                                degcur, msum);
    cast_pad_x<<<8192, 256, 0, stream>>>((const float4*)x, xb);

    // --- CSR build ---
    count_deg<<<EB, 256, 0, stream>>>(ei, degcur);
    scan_bsum<<<SCAN_NB, 256, 0, stream>>>(degcur, spart);
    scan_part<<<1, 256, 0, stream>>>(spart);
    scan_write<<<SCAN_NB, 256, 0, stream>>>(degcur, spart, rowptr);
    fill_csr<<<EB, 256, 0, stream>>>(ei, rowptr, cur, esrc, edst);

    // --- cross attention: Q|K|V in one dispatch, then gate ---
    gemm_qkv<<<dim3(3, MT), 256, 0, stream>>>(xb, wqT, wkT, wvT, qb, kb, vb);
    node_attn_b<<<NN, 128, 0, stream>>>(qb, kb, vb);

    // --- h0 = [x_struct | attn] @ Wo + bo ---
    gemm_mfma<1, 0, 1><<<dim3(1, MT), 256, 0, stream>>>(xb, 896, 128, vb, 128, 128, woT, h0b, 128, bo,
                                                        nullptr, nullptr, nullptr, nullptr);

    // --- h1 = [h0 | x_sem] @ W1 (XCD-swizzled 1D grid, no fused dots) ---
    gemm_w1<<<4 * MT, 256, 0, stream>>>(h0b, xb + 128, w1T, h1b);

    // --- GAT layer 1: dots -> CSR-ordered edge exp -> barrier-free gather ---
    att_dots1_b<<<NN, 256, 0, stream>>>(h1b, as1, ad1, asrc, adst);
    edge_exp<NHEADS><<<EB, 256, 0, stream>>>(esrc, edst, asrc, adst, exf);
    agg1_f<<<NN, 128, 0, stream>>>(rowptr, esrc, exf, h1b, b1, o1b);

    // --- graph norm 1 + ELU (bf16 in place) ---
    colstat_b<<<(NN + 127) / 128, H1D, 0, stream>>>(o1b, msum, vsum, NN, 128);
    apply_norm_elu_b<<<(NN + 127) / 128, H1D, 0, stream>>>(o1b, msum, vsum, g1m, g1w, g1b, NN, 128);

    // --- GAT layer 2: W2 GEMM with fused att-dots (cheap: 391 blocks) ---
    gemm_mfma<1, 1, 1><<<dim3(1, MT), 256, 0, stream>>>(o1b, 512, 512, (const u16*)nullptr, 0, 0, w2T, h2b, 128,
                                                        nullptr, as2, ad2, asrc, adst);
    edge_exp<1><<<EB, 256, 0, stream>>>(esrc, edst, asrc, adst, exf);
    agg2_f<<<(NN + 3) / 4, 256, 0, stream>>>(rowptr, esrc, exf, h2b, b2, o2, msum);

    // --- graph norm 2 + ELU + projection (fused) ---
    colstat<<<(NN + 127) / 128, HIDD, 0, stream>>>(o2, msum, vsum, NN, 128);
    norm2_proj<<<NN, 128, 0, stream>>>(o2, msum, vsum, g2m, g2w, g2b, Wn, bn, out);
}